// Round 7
// baseline (224.158 us; speedup 1.0000x reference)
//
#include <hip/hip_runtime.h>

// ---------------------------------------------------------------------------
// Pipeline (algebraically restructured from the reference):
//   Xs[8][N][32]  = bf16(node_features) slice-major   (32-ch slices, 3.2 MB
//   Hs[2][Nh][64] = bf16(hedge_features) slice-major   each: L2-resident)
//   A[n,:]  = sum_{e: rcv=n} conv_e * X[snd_e,:]      (f32 acc -> bf16)
//   c1[n]   = sum conv_e ;  B, c2 analogous for hedges
//   out     = (A@Wm + c1*bm) .* (B@Ws + c2*bs)        (bf16 MFMA, f32 accum)
//
// Scatter kernels are XCD-pinned: blocks round-robin over 8 XCDs, so
// slice = bid & 7 (node) / bid & 1 (hedge) keeps each XCD's gather stream
// inside its own private-L2-resident sub-table.
// ---------------------------------------------------------------------------

typedef __attribute__((ext_vector_type(8))) short bf16x8;
typedef __attribute__((ext_vector_type(4))) float f32x4;

static __device__ __forceinline__ unsigned short f2bf(float f) {
  unsigned u = __float_as_uint(f);
  u += 0x7fff + ((u >> 16) & 1);          // round-to-nearest-even
  return (unsigned short)(u >> 16);
}
static __device__ __forceinline__ float bf2f(unsigned short h) {
  return __uint_as_float((unsigned)h << 16);
}

// ---------------------------------------------------------------------------
// prep_all: blockIdx ranges ->
//   [0,bX)     : cvt X f32 -> Xs[8][N][32] bf16 slice-major
//   [bX,+bH)   : cvt H f32 -> Hs[2][Nh][64] bf16 slice-major
//   [..,+bE1)  : row offsets for node_receivers
//   [..,+bE2)  : row offsets for h2n_receivers
//   [..,+64)   : transpose Wm (256x256) -> WmT bf16
//   [..,+32)   : transpose Ws (128x256) -> WsT bf16
// ---------------------------------------------------------------------------
__global__ __launch_bounds__(256) void prep_all(
    const float* __restrict__ X, const float* __restrict__ H,
    const int* __restrict__ rcv1, int E1,
    const int* __restrict__ rcv2, int E2, int N, int Nh,
    const float* __restrict__ Wm, const float* __restrict__ Ws,
    unsigned short* __restrict__ Xs, unsigned short* __restrict__ Hs,
    int* __restrict__ ro1, int* __restrict__ ro2,
    unsigned short* __restrict__ WmT, unsigned short* __restrict__ WsT,
    int nX4, int nH4)
{
  __shared__ float t[32][33];
  const int tid = (int)threadIdx.x;
  int b = (int)blockIdx.x;

  const int bX  = (nX4 + 255) / 256;
  const int bH  = (nH4 + 255) / 256;
  const int bE1 = (E1 + 255) / 256;
  const int bE2 = (E2 + 255) / 256;

  if (b < bX) {                       // ---- cvt X -> slice-major ----
    const int i = b * 256 + tid;
    if (i < nX4) {
      const float4 v = reinterpret_cast<const float4*>(X)[i];
      const int n = i >> 6, c4 = i & 63;          // 64 float4 per row
      const int slice = c4 >> 3;                  // 8 float4 per slice
      const int woff = (c4 & 7) * 4;
      *reinterpret_cast<ushort4*>(
          Xs + (size_t)slice * N * 32 + (size_t)n * 32 + woff) =
          make_ushort4(f2bf(v.x), f2bf(v.y), f2bf(v.z), f2bf(v.w));
    }
    return;
  }
  b -= bX;
  if (b < bH) {                       // ---- cvt H -> slice-major ----
    const int i = b * 256 + tid;
    if (i < nH4) {
      const float4 v = reinterpret_cast<const float4*>(H)[i];
      const int n = i >> 5, c4 = i & 31;          // 32 float4 per row
      const int slice = c4 >> 4;                  // 16 float4 per slice
      const int woff = (c4 & 15) * 4;
      *reinterpret_cast<ushort4*>(
          Hs + (size_t)slice * Nh * 64 + (size_t)n * 64 + woff) =
          make_ushort4(f2bf(v.x), f2bf(v.y), f2bf(v.z), f2bf(v.w));
    }
    return;
  }
  b -= bH;
  if (b < bE1) {                      // ---- row offsets 1 ----
    const int e = b * 256 + tid;
    if (e < E1) {
      const int c = rcv1[e];
      const int p = (e == 0) ? -1 : rcv1[e - 1];
      for (int n = p + 1; n <= c; ++n) ro1[n] = e;
      if (e == E1 - 1)
        for (int n = c + 1; n <= N; ++n) ro1[n] = E1;
    }
    return;
  }
  b -= bE1;
  if (b < bE2) {                      // ---- row offsets 2 ----
    const int e = b * 256 + tid;
    if (e < E2) {
      const int c = rcv2[e];
      const int p = (e == 0) ? -1 : rcv2[e - 1];
      for (int n = p + 1; n <= c; ++n) ro2[n] = e;
      if (e == E2 - 1)
        for (int n = c + 1; n <= N; ++n) ro2[n] = E2;
    }
    return;
  }
  b -= bE2;
  {
    // ---- weight transposes: Wm tiles [0,64), Ws tiles [64,96) ----
    const float* W; unsigned short* WT; int K, Nn, tile;
    if (b < 64) { W = Wm; WT = WmT; K = 256; Nn = 256; tile = b; }
    else        { W = Ws; WT = WsT; K = 128; Nn = 256; tile = b - 64; }
    const int ntiles_n = Nn / 32;
    const int n0 = (tile % ntiles_n) * 32;
    const int k0 = (tile / ntiles_n) * 32;
    const int tx = tid & 31, ty = tid >> 5;   // 32 x 8
#pragma unroll
    for (int i = 0; i < 32; i += 8)
      t[ty + i][tx] = W[(size_t)(k0 + ty + i) * Nn + n0 + tx];
    __syncthreads();
#pragma unroll
    for (int i = 0; i < 32; i += 8)
      WT[(size_t)(n0 + ty + i) * K + k0 + tx] = f2bf(t[tx][ty + i]);
  }
}

// ---------------------------------------------------------------------------
// Node scatter, XCD-pinned 32-channel slices.
// Grid: ceil(N/4)*8 blocks of 256; slice = bid&7 (lands on XCD bid%8),
// 4 waves/block = 4 nodes. Lane: esub = l>>4 (edge subgroup), chp = l&15
// (channel pair). 4 edges in flight per step, unrolled x2.
// ---------------------------------------------------------------------------
__global__ __launch_bounds__(256) void scatter_node_xcd(
    const unsigned short* __restrict__ Xs,   // [8][N][32] bf16
    const int* __restrict__ snd,
    const float* __restrict__ conv,
    const int* __restrict__ ro,              // [N+1]
    unsigned short* __restrict__ A,          // [Mp,256] bf16
    float* __restrict__ c1,                  // [Mp]
    int N)
{
  const int lane = threadIdx.x & 63;
  const int bid = (int)blockIdx.x;
  const int slice = bid & 7;
  const int node = __builtin_amdgcn_readfirstlane(
      (bid >> 3) * 4 + ((int)threadIdx.x >> 6));
  if (node >= N) return;

  const int lo = ro[node];
  const int hi = ro[node + 1];

  const int esub = lane >> 4;          // 0..3
  const int chp  = lane & 15;          // channel pair within slice
  const unsigned short* Xsl = Xs + (size_t)slice * N * 32 + chp * 2;
  const int* sp   = snd + esub;
  const float* cp = conv + esub;

  float2 acc = make_float2(0.f, 0.f);
  float cacc = 0.f;

  int e = lo;
  for (; e + 8 <= hi; e += 8) {        // 2 independent gathers in flight
    const int s0 = sp[e], s1 = sp[e + 4];
    const float cv0 = cp[e], cv1 = cp[e + 4];
    const ushort2 x0 = *reinterpret_cast<const ushort2*>(Xsl + (size_t)s0 * 32);
    const ushort2 x1 = *reinterpret_cast<const ushort2*>(Xsl + (size_t)s1 * 32);
    acc.x = fmaf(cv0, bf2f(x0.x), acc.x);
    acc.y = fmaf(cv0, bf2f(x0.y), acc.y);
    acc.x = fmaf(cv1, bf2f(x1.x), acc.x);
    acc.y = fmaf(cv1, bf2f(x1.y), acc.y);
    cacc += cv0 + cv1;
  }
  for (; e < hi; e += 4) {             // masked tail, <=2 iters
    const int idx = e + esub;
    const bool v = idx < hi;
    const int ic = v ? idx : (hi - 1);
    const int s = snd[ic];
    const float cv = v ? conv[ic] : 0.f;
    const ushort2 x = *reinterpret_cast<const ushort2*>(Xsl + (size_t)s * 32);
    acc.x = fmaf(cv, bf2f(x.x), acc.x);
    acc.y = fmaf(cv, bf2f(x.y), acc.y);
    cacc += cv;
  }

  // reduce across the 4 edge subgroups (lanes l, l^16, l^32, l^48)
  acc.x += __shfl_xor(acc.x, 16); acc.x += __shfl_xor(acc.x, 32);
  acc.y += __shfl_xor(acc.y, 16); acc.y += __shfl_xor(acc.y, 32);

  if (lane < 16) {
    *reinterpret_cast<ushort2*>(A + (size_t)node * 256 + slice * 32 + chp * 2) =
        make_ushort2(f2bf(acc.x), f2bf(acc.y));
  }
  if (slice == 0 && lane == 0) {
    cacc += __shfl_xor(cacc, 16); // lane0 result only needs its own chain:
  }
  // conv-sum: every lane already holds its subgroup's sum; combine subgroups
  if (slice == 0) {
    float cs = cacc;
    cs += __shfl_xor(cs, 16); cs += __shfl_xor(cs, 32);
    if (lane == 0) c1[node] = cs;
  }
}

// ---------------------------------------------------------------------------
// Hedge scatter, XCD-pinned 64-channel slices (even/odd XCDs).
// Grid: ceil(N/4)*2; slice = bid&1. Lane: esub = l>>5, chp = l&31.
// ---------------------------------------------------------------------------
__global__ __launch_bounds__(256) void scatter_hedge_xcd(
    const unsigned short* __restrict__ Hs,   // [2][Nh][64] bf16
    const int* __restrict__ snd,
    const float* __restrict__ conv,
    const int* __restrict__ ro,              // [N+1]
    unsigned short* __restrict__ B,          // [Mp,128] bf16
    float* __restrict__ c2,                  // [Mp]
    int N, int Nh)
{
  const int lane = threadIdx.x & 63;
  const int bid = (int)blockIdx.x;
  const int slice = bid & 1;
  const int node = __builtin_amdgcn_readfirstlane(
      (bid >> 1) * 4 + ((int)threadIdx.x >> 6));
  if (node >= N) return;

  const int lo = ro[node];
  const int hi = ro[node + 1];

  const int esub = lane >> 5;          // 0..1
  const int chp  = lane & 31;
  const unsigned short* Hl = Hs + (size_t)slice * Nh * 64 + chp * 2;
  const int* sp   = snd + esub;
  const float* cp = conv + esub;

  float2 acc = make_float2(0.f, 0.f);
  float cacc = 0.f;

  int e = lo;
  for (; e + 4 <= hi; e += 4) {        // 2 independent gathers in flight
    const int s0 = sp[e], s1 = sp[e + 2];
    const float cv0 = cp[e], cv1 = cp[e + 2];
    const ushort2 x0 = *reinterpret_cast<const ushort2*>(Hl + (size_t)s0 * 64);
    const ushort2 x1 = *reinterpret_cast<const ushort2*>(Hl + (size_t)s1 * 64);
    acc.x = fmaf(cv0, bf2f(x0.x), acc.x);
    acc.y = fmaf(cv0, bf2f(x0.y), acc.y);
    acc.x = fmaf(cv1, bf2f(x1.x), acc.x);
    acc.y = fmaf(cv1, bf2f(x1.y), acc.y);
    cacc += cv0 + cv1;
  }
  for (; e < hi; e += 2) {             // masked tail
    const int idx = e + esub;
    const bool v = idx < hi;
    const int ic = v ? idx : (hi - 1);
    const int s = snd[ic];
    const float cv = v ? conv[ic] : 0.f;
    const ushort2 x = *reinterpret_cast<const ushort2*>(Hl + (size_t)s * 64);
    acc.x = fmaf(cv, bf2f(x.x), acc.x);
    acc.y = fmaf(cv, bf2f(x.y), acc.y);
    cacc += cv;
  }

  acc.x += __shfl_xor(acc.x, 32);
  acc.y += __shfl_xor(acc.y, 32);

  if (lane < 32) {
    *reinterpret_cast<ushort2*>(B + (size_t)node * 128 + slice * 64 + chp * 2) =
        make_ushort2(f2bf(acc.x), f2bf(acc.y));
  }
  if (slice == 0) {
    float cs = cacc;
    cs += __shfl_xor(cs, 32);
    if (lane == 0) c2[node] = cs;
  }
}

// ---------------------------------------------------------------------------
// MFMA dual-GEMM + bias + Hadamard, LDS-cached weight slice.
// Grid: (Mp/256, 4). Block = 512 threads = 8 waves; block tile 256 rows x
// 64 cols. Wave owns 32 rows x 64 cols (2 m-sub x 4 n-sub of 16x16).
// mfma_f32_16x16x32_bf16 fragments:
//   A-frag: row = lane&15, k = 8*(lane>>4) + j
//   B-frag: col = lane&15, k = 8*(lane>>4) + j
//   C/D   : col = lane&15, row = 4*(lane>>4) + reg   [m89-verified]
// ---------------------------------------------------------------------------
__global__ __launch_bounds__(512) void gemm_combine_mfma(
    const unsigned short* __restrict__ A,    // [Mp,256] bf16
    const unsigned short* __restrict__ B,    // [Mp,128] bf16
    const float* __restrict__ c1,            // [Mp]
    const float* __restrict__ c2,            // [Mp]
    const unsigned short* __restrict__ WmT,  // [256,256] bf16 (N-major)
    const float* __restrict__ bm,            // [256]
    const unsigned short* __restrict__ WsT,  // [256,128] bf16 (N-major)
    const float* __restrict__ bs,            // [256]
    float* __restrict__ out,                 // [M,256]
    int M)
{
  __shared__ unsigned short lWm[64][264];    // 64 cols x 256 K, +8 pad
  __shared__ unsigned short lWs[64][136];    // 64 cols x 128 K, +8 pad

  const int tid  = (int)threadIdx.x;
  const int lane = tid & 63;
  const int wv   = tid >> 6;          // 0..7
  const int l15  = lane & 15;
  const int lg   = lane >> 4;         // 0..3
  const int m0      = blockIdx.x * 256;
  const int colBlk  = blockIdx.y * 64;

  // ---- stage weight slices into LDS ----
  for (int i = tid; i < 64 * 256 / 8; i += 512) {       // 2048 x 16B
    const int c = i >> 5, k8 = (i & 31) << 3;
    *reinterpret_cast<bf16x8*>(&lWm[c][k8]) =
        *reinterpret_cast<const bf16x8*>(WmT + (size_t)(colBlk + c) * 256 + k8);
  }
  for (int i = tid; i < 64 * 128 / 8; i += 512) {       // 1024 x 16B
    const int c = i >> 4, k8 = (i & 15) << 3;
    *reinterpret_cast<bf16x8*>(&lWs[c][k8]) =
        *reinterpret_cast<const bf16x8*>(WsT + (size_t)(colBlk + c) * 128 + k8);
  }
  __syncthreads();

  const int rowA = m0 + wv * 32 + l15;

  f32x4 accM[2][4];
  f32x4 accS[2][4];
#pragma unroll
  for (int ms = 0; ms < 2; ++ms)
#pragma unroll
    for (int n = 0; n < 4; ++n) {
      accM[ms][n] = (f32x4)0.f;
      accS[ms][n] = (f32x4)0.f;
    }

  // ---- accM = A @ Wm, K = 256 ----
#pragma unroll
  for (int kc = 0; kc < 256; kc += 32) {
    const int ko = kc + lg * 8;
    const bf16x8 a0 = *reinterpret_cast<const bf16x8*>(A + (size_t)rowA * 256 + ko);
    const bf16x8 a1 = *reinterpret_cast<const bf16x8*>(A + (size_t)(rowA + 16) * 256 + ko);
#pragma unroll
    for (int n = 0; n < 4; ++n) {
      const bf16x8 w = *reinterpret_cast<const bf16x8*>(&lWm[l15 + n * 16][ko]);
      accM[0][n] = __builtin_amdgcn_mfma_f32_16x16x32_bf16(a0, w, accM[0][n], 0, 0, 0);
      accM[1][n] = __builtin_amdgcn_mfma_f32_16x16x32_bf16(a1, w, accM[1][n], 0, 0, 0);
    }
  }

  // ---- accS = B @ Ws, K = 128 ----
#pragma unroll
  for (int kc = 0; kc < 128; kc += 32) {
    const int ko = kc + lg * 8;
    const bf16x8 b0 = *reinterpret_cast<const bf16x8*>(B + (size_t)rowA * 128 + ko);
    const bf16x8 b1 = *reinterpret_cast<const bf16x8*>(B + (size_t)(rowA + 16) * 128 + ko);
#pragma unroll
    for (int n = 0; n < 4; ++n) {
      const bf16x8 w = *reinterpret_cast<const bf16x8*>(&lWs[l15 + n * 16][ko]);
      accS[0][n] = __builtin_amdgcn_mfma_f32_16x16x32_bf16(b0, w, accS[0][n], 0, 0, 0);
      accS[1][n] = __builtin_amdgcn_mfma_f32_16x16x32_bf16(b1, w, accS[1][n], 0, 0, 0);
    }
  }

  // ---- epilogue: (accM + c1*bm) .* (accS + c2*bs) ----
  float bmv[4], bsv[4];
#pragma unroll
  for (int n = 0; n < 4; ++n) {
    bmv[n] = bm[colBlk + n * 16 + l15];
    bsv[n] = bs[colBlk + n * 16 + l15];
  }
#pragma unroll
  for (int ms = 0; ms < 2; ++ms) {
    const int rbase = m0 + wv * 32 + ms * 16 + lg * 4;
#pragma unroll
    for (int r = 0; r < 4; ++r) {
      const int row = rbase + r;
      if (row < M) {
        const float k1 = c1[row];
        const float k2 = c2[row];
#pragma unroll
        for (int n = 0; n < 4; ++n) {
          const int col = colBlk + n * 16 + l15;
          const float mv = accM[ms][n][r] + k1 * bmv[n];
          const float sv = accS[ms][n][r] + k2 * bsv[n];
          out[(size_t)row * 256 + col] = mv * sv;
        }
      }
    }
  }
}

extern "C" void kernel_launch(void* const* d_in, const int* in_sizes, int n_in,
                              void* d_out, int out_size, void* d_ws, size_t ws_size,
                              hipStream_t stream) {
  const float* node_features  = (const float*)d_in[0];   // [50000,256]
  const float* hedge_features = (const float*)d_in[1];   // [25000,128]
  const int*   node_senders   = (const int*)d_in[2];     // [E]
  const int*   node_receivers = (const int*)d_in[3];     // [E] sorted
  const float* node_conv      = (const float*)d_in[4];   // [E]
  const int*   h2n_senders    = (const int*)d_in[5];     // [E2]
  const int*   h2n_receivers  = (const int*)d_in[6];     // [E2] sorted
  const float* h2n_conv       = (const float*)d_in[7];   // [E2]
  const float* Wm             = (const float*)d_in[8];   // [256,256]
  const float* bm             = (const float*)d_in[9];   // [256]
  const float* Ws             = (const float*)d_in[10];  // [128,256]
  const float* bs             = (const float*)d_in[11];  // [256]
  float* out = (float*)d_out;

  const int M   = in_sizes[0] / 256;       // 50000 nodes
  const int Nh  = in_sizes[1] / 128;       // 25000 hedges
  const int E   = in_sizes[2];             // 800000
  const int E2  = in_sizes[5];             // 400000
  const int Mp  = ((M + 255) / 256) * 256; // padded rows for 256-row GEMM tiles

  // Workspace layout (bf16 = unsigned short):
  //   A[Mp,256] | B[Mp,128] | Xs[8][M][32] | Hs[2][Nh][64]
  //   | WmT[256,256] | WsT[256,128] | c1 f32[Mp] | c2 f32[Mp] | ro1 | ro2
  unsigned short* Ab  = (unsigned short*)d_ws;
  unsigned short* Bb  = Ab + (size_t)Mp * 256;
  unsigned short* Xs  = Bb + (size_t)Mp * 128;
  unsigned short* Hs  = Xs + (size_t)M * 256;
  unsigned short* WmT = Hs + (size_t)Nh * 128;
  unsigned short* WsT = WmT + 256 * 256;
  float* c1 = (float*)(WsT + 256 * 128);
  float* c2 = c1 + Mp;
  int*   ro1 = (int*)(c2 + Mp);
  int*   ro2 = ro1 + (M + 1);

  const int nX4 = M * 256 / 4, nH4 = Nh * 128 / 4;
  const int bX  = (nX4 + 255) / 256;
  const int bH  = (nH4 + 255) / 256;
  const int bE1 = (E + 255) / 256;
  const int bE2 = (E2 + 255) / 256;
  const int prep_blocks = bX + bH + bE1 + bE2 + 64 + 32;

  prep_all<<<prep_blocks, 256, 0, stream>>>(
      node_features, hedge_features,
      node_receivers, E, h2n_receivers, E2, M, Nh,
      Wm, Ws, Xs, Hs, ro1, ro2, WmT, WsT, nX4, nH4);

  const int nodeBlks = (M + 3) / 4;
  scatter_node_xcd<<<nodeBlks * 8, 256, 0, stream>>>(
      Xs, node_senders, node_conv, ro1, Ab, c1, M);
  scatter_hedge_xcd<<<nodeBlks * 2, 256, 0, stream>>>(
      Hs, h2n_senders, h2n_conv, ro2, Bb, c2, M, Nh);

  gemm_combine_mfma<<<dim3(Mp / 256, 4), 512, 0, stream>>>(
      Ab, Bb, c1, c2, WmT, bm, WsT, bs, out, M);
}

// Round 8
// 215.669 us; speedup vs baseline: 1.0394x; 1.0394x over previous
//
#include <hip/hip_runtime.h>

// ---------------------------------------------------------------------------
// Pipeline (algebraically restructured from the reference):
//   Xs[8][N][32]  = bf16(node_features) slice-major   (32-ch slices, 3.2 MB
//   Hs[2][Nh][64] = bf16(hedge_features) slice-major   each: L2-resident)
//   A[n,:]  = sum_{e: rcv=n} conv_e * X[snd_e,:]      (f32 acc -> bf16)
//   c1[n]   = sum conv_e ;  B, c2 analogous for hedges
//   out     = (A@Wm + c1*bm) .* (B@Ws + c2*bs)        (bf16 MFMA, f32 accum)
//
// Scatter kernels are XCD-pinned (slice = bid & 7 / bid & 1, XCD = bid % 8)
// with an 8-edges-per-wave-instruction schedule: lane = (edge-slot, ch-group),
// 8 B/lane gathers, unmasked main loop + single masked tail, grid-stride
// persistent blocks. R6 proved the locality (FETCH 215->59 MB); this round
// fixes the instruction schedule that made R6 issue-bound.
// ---------------------------------------------------------------------------

typedef __attribute__((ext_vector_type(8))) short bf16x8;
typedef __attribute__((ext_vector_type(8))) unsigned short u16x8;
typedef __attribute__((ext_vector_type(4))) float f32x4;

static __device__ __forceinline__ unsigned short f2bf(float f) {
  unsigned u = __float_as_uint(f);
  u += 0x7fff + ((u >> 16) & 1);          // round-to-nearest-even
  return (unsigned short)(u >> 16);
}
static __device__ __forceinline__ float bf2f(unsigned short h) {
  return __uint_as_float((unsigned)h << 16);
}

// ---------------------------------------------------------------------------
// prep_all: blockIdx ranges ->
//   [0,bX)     : cvt X f32 -> Xs[8][N][32] bf16 slice-major
//   [bX,+bH)   : cvt H f32 -> Hs[2][Nh][64] bf16 slice-major
//   [..,+bE1)  : row offsets for node_receivers
//   [..,+bE2)  : row offsets for h2n_receivers
//   [..,+64)   : transpose Wm (256x256) -> WmT bf16
//   [..,+32)   : transpose Ws (128x256) -> WsT bf16
// ---------------------------------------------------------------------------
__global__ __launch_bounds__(256) void prep_all(
    const float* __restrict__ X, const float* __restrict__ H,
    const int* __restrict__ rcv1, int E1,
    const int* __restrict__ rcv2, int E2, int N, int Nh,
    const float* __restrict__ Wm, const float* __restrict__ Ws,
    unsigned short* __restrict__ Xs, unsigned short* __restrict__ Hs,
    int* __restrict__ ro1, int* __restrict__ ro2,
    unsigned short* __restrict__ WmT, unsigned short* __restrict__ WsT,
    int nX4, int nH4)
{
  __shared__ float t[32][33];
  const int tid = (int)threadIdx.x;
  int b = (int)blockIdx.x;

  const int bX  = (nX4 + 255) / 256;
  const int bH  = (nH4 + 255) / 256;
  const int bE1 = (E1 + 255) / 256;
  const int bE2 = (E2 + 255) / 256;

  if (b < bX) {                       // ---- cvt X -> slice-major ----
    const int i = b * 256 + tid;
    if (i < nX4) {
      const float4 v = reinterpret_cast<const float4*>(X)[i];
      const int n = i >> 6, c4 = i & 63;          // 64 float4 per row
      const int slice = c4 >> 3;                  // 8 float4 per slice
      const int woff = (c4 & 7) * 4;
      *reinterpret_cast<ushort4*>(
          Xs + (size_t)slice * N * 32 + (size_t)n * 32 + woff) =
          make_ushort4(f2bf(v.x), f2bf(v.y), f2bf(v.z), f2bf(v.w));
    }
    return;
  }
  b -= bX;
  if (b < bH) {                       // ---- cvt H -> slice-major ----
    const int i = b * 256 + tid;
    if (i < nH4) {
      const float4 v = reinterpret_cast<const float4*>(H)[i];
      const int n = i >> 5, c4 = i & 31;          // 32 float4 per row
      const int slice = c4 >> 4;                  // 16 float4 per slice
      const int woff = (c4 & 15) * 4;
      *reinterpret_cast<ushort4*>(
          Hs + (size_t)slice * Nh * 64 + (size_t)n * 64 + woff) =
          make_ushort4(f2bf(v.x), f2bf(v.y), f2bf(v.z), f2bf(v.w));
    }
    return;
  }
  b -= bH;
  if (b < bE1) {                      // ---- row offsets 1 ----
    const int e = b * 256 + tid;
    if (e < E1) {
      const int c = rcv1[e];
      const int p = (e == 0) ? -1 : rcv1[e - 1];
      for (int n = p + 1; n <= c; ++n) ro1[n] = e;
      if (e == E1 - 1)
        for (int n = c + 1; n <= N; ++n) ro1[n] = E1;
    }
    return;
  }
  b -= bE1;
  if (b < bE2) {                      // ---- row offsets 2 ----
    const int e = b * 256 + tid;
    if (e < E2) {
      const int c = rcv2[e];
      const int p = (e == 0) ? -1 : rcv2[e - 1];
      for (int n = p + 1; n <= c; ++n) ro2[n] = e;
      if (e == E2 - 1)
        for (int n = c + 1; n <= N; ++n) ro2[n] = E2;
    }
    return;
  }
  b -= bE2;
  {
    // ---- weight transposes: Wm tiles [0,64), Ws tiles [64,96) ----
    const float* W; unsigned short* WT; int K, Nn, tile;
    if (b < 64) { W = Wm; WT = WmT; K = 256; Nn = 256; tile = b; }
    else        { W = Ws; WT = WsT; K = 128; Nn = 256; tile = b - 64; }
    const int ntiles_n = Nn / 32;
    const int n0 = (tile % ntiles_n) * 32;
    const int k0 = (tile / ntiles_n) * 32;
    const int tx = tid & 31, ty = tid >> 5;   // 32 x 8
#pragma unroll
    for (int i = 0; i < 32; i += 8)
      t[ty + i][tx] = W[(size_t)(k0 + ty + i) * Nn + n0 + tx];
    __syncthreads();
#pragma unroll
    for (int i = 0; i < 32; i += 8)
      WT[(size_t)(n0 + ty + i) * K + k0 + tx] = f2bf(t[tx][ty + i]);
  }
}

// ---------------------------------------------------------------------------
// Node scatter, XCD-pinned 32-ch slices, 8 edges per wave-instruction.
// lane: el = lane>>3 (edge slot 0..7), cg = lane&7 (4-ch group).
// One wave per (node, slice); grid-stride over nodes; slice = bid & 7.
// ---------------------------------------------------------------------------
__global__ __launch_bounds__(256) void scatter_node_slice(
    const unsigned short* __restrict__ Xs,   // [8][N][32] bf16
    const int* __restrict__ snd,
    const float* __restrict__ conv,
    const int* __restrict__ ro,              // [N+1]
    unsigned short* __restrict__ A,          // [Mp,256] bf16
    float* __restrict__ c1,                  // [Mp]
    int N)
{
  const int tid  = (int)threadIdx.x;
  const int lane = tid & 63;
  const int wv   = tid >> 6;
  const int bid  = (int)blockIdx.x;
  const int slice = bid & 7;
  const int el = lane >> 3;            // edge slot
  const int cg = lane & 7;             // channel group (4 ch)
  const int sliceWaves = ((int)gridDim.x >> 3) * 4;

  const unsigned short* Xb = Xs + (size_t)slice * N * 32 + cg * 4;

  for (int node = (bid >> 3) * 4 + wv; node < N; node += sliceWaves) {
    const int lo = ro[node];
    const int hi = ro[node + 1];
    const int nfull = (hi - lo) & ~7;

    float4 acc = make_float4(0.f, 0.f, 0.f, 0.f);
    float cacc = 0.f;

    int e0 = lo;
    for (; e0 < lo + nfull; e0 += 8) {         // unmasked: 8 edges/iter
      const int e = e0 + el;
      const int s = snd[e];
      const float cv = conv[e];
      const ushort4 x = *reinterpret_cast<const ushort4*>(Xb + (size_t)s * 32);
      acc.x = fmaf(cv, bf2f(x.x), acc.x);
      acc.y = fmaf(cv, bf2f(x.y), acc.y);
      acc.z = fmaf(cv, bf2f(x.z), acc.z);
      acc.w = fmaf(cv, bf2f(x.w), acc.w);
      cacc += cv;
    }
    if (e0 < hi) {                              // single masked tail
      const int e = e0 + el;
      const bool v = e < hi;
      const int ec = v ? e : (hi - 1);
      const int s = snd[ec];
      const float cv = v ? conv[ec] : 0.f;
      const ushort4 x = *reinterpret_cast<const ushort4*>(Xb + (size_t)s * 32);
      acc.x = fmaf(cv, bf2f(x.x), acc.x);
      acc.y = fmaf(cv, bf2f(x.y), acc.y);
      acc.z = fmaf(cv, bf2f(x.z), acc.z);
      acc.w = fmaf(cv, bf2f(x.w), acc.w);
      cacc += cv;
    }

    // reduce across the 8 edge slots (xor strides 8,16,32)
    acc.x += __shfl_xor(acc.x, 8);  acc.y += __shfl_xor(acc.y, 8);
    acc.z += __shfl_xor(acc.z, 8);  acc.w += __shfl_xor(acc.w, 8);
    acc.x += __shfl_xor(acc.x, 16); acc.y += __shfl_xor(acc.y, 16);
    acc.z += __shfl_xor(acc.z, 16); acc.w += __shfl_xor(acc.w, 16);
    acc.x += __shfl_xor(acc.x, 32); acc.y += __shfl_xor(acc.y, 32);
    acc.z += __shfl_xor(acc.z, 32); acc.w += __shfl_xor(acc.w, 32);

    if (slice == 0) {
      cacc += __shfl_xor(cacc, 8);
      cacc += __shfl_xor(cacc, 16);
      cacc += __shfl_xor(cacc, 32);
      if (lane == 0) c1[node] = cacc;
    }
    if (el == 0) {
      *reinterpret_cast<ushort4*>(
          A + (size_t)node * 256 + slice * 32 + cg * 4) =
          make_ushort4(f2bf(acc.x), f2bf(acc.y), f2bf(acc.z), f2bf(acc.w));
    }
  }
}

// ---------------------------------------------------------------------------
// Hedge scatter, XCD-pinned 64-ch slices (even/odd XCDs), 8 edges per
// wave-instruction. lane: el = lane>>3, cg = lane&7 (8-ch group, ushort8).
// ---------------------------------------------------------------------------
__global__ __launch_bounds__(256) void scatter_hedge_slice(
    const unsigned short* __restrict__ Hs,   // [2][Nh][64] bf16
    const int* __restrict__ snd,
    const float* __restrict__ conv,
    const int* __restrict__ ro,              // [N+1]
    unsigned short* __restrict__ B,          // [Mp,128] bf16
    float* __restrict__ c2,                  // [Mp]
    int N, int Nh)
{
  const int tid  = (int)threadIdx.x;
  const int lane = tid & 63;
  const int wv   = tid >> 6;
  const int bid  = (int)blockIdx.x;
  const int slice = bid & 1;
  const int el = lane >> 3;
  const int cg = lane & 7;             // channel group (8 ch)
  const int sliceWaves = ((int)gridDim.x >> 1) * 4;

  const unsigned short* Hb = Hs + (size_t)slice * Nh * 64 + cg * 8;

  for (int node = (bid >> 1) * 4 + wv; node < N; node += sliceWaves) {
    const int lo = ro[node];
    const int hi = ro[node + 1];
    const int nfull = (hi - lo) & ~7;

    float acc[8];
#pragma unroll
    for (int k = 0; k < 8; ++k) acc[k] = 0.f;
    float cacc = 0.f;

    int e0 = lo;
    for (; e0 < lo + nfull; e0 += 8) {
      const int e = e0 + el;
      const int s = snd[e];
      const float cv = conv[e];
      const u16x8 x = *reinterpret_cast<const u16x8*>(Hb + (size_t)s * 64);
#pragma unroll
      for (int k = 0; k < 8; ++k)
        acc[k] = fmaf(cv, bf2f((unsigned short)x[k]), acc[k]);
      cacc += cv;
    }
    if (e0 < hi) {
      const int e = e0 + el;
      const bool v = e < hi;
      const int ec = v ? e : (hi - 1);
      const int s = snd[ec];
      const float cv = v ? conv[ec] : 0.f;
      const u16x8 x = *reinterpret_cast<const u16x8*>(Hb + (size_t)s * 64);
#pragma unroll
      for (int k = 0; k < 8; ++k)
        acc[k] = fmaf(cv, bf2f((unsigned short)x[k]), acc[k]);
      cacc += cv;
    }

#pragma unroll
    for (int k = 0; k < 8; ++k) {
      acc[k] += __shfl_xor(acc[k], 8);
      acc[k] += __shfl_xor(acc[k], 16);
      acc[k] += __shfl_xor(acc[k], 32);
    }

    if (slice == 0) {
      cacc += __shfl_xor(cacc, 8);
      cacc += __shfl_xor(cacc, 16);
      cacc += __shfl_xor(cacc, 32);
      if (lane == 0) c2[node] = cacc;
    }
    if (el == 0) {
      u16x8 r;
#pragma unroll
      for (int k = 0; k < 8; ++k) r[k] = f2bf(acc[k]);
      *reinterpret_cast<u16x8*>(
          B + (size_t)node * 128 + slice * 64 + cg * 8) = r;
    }
  }
}

// ---------------------------------------------------------------------------
// MFMA dual-GEMM + bias + Hadamard, LDS-cached weight slice.
// Grid: (Mp/256, 4). Block = 512 threads = 8 waves; block tile 256 rows x
// 64 cols. Wave owns 32 rows x 64 cols (2 m-sub x 4 n-sub of 16x16).
// mfma_f32_16x16x32_bf16 fragments:
//   A-frag: row = lane&15, k = 8*(lane>>4) + j
//   B-frag: col = lane&15, k = 8*(lane>>4) + j
//   C/D   : col = lane&15, row = 4*(lane>>4) + reg   [m89-verified]
// ---------------------------------------------------------------------------
__global__ __launch_bounds__(512) void gemm_combine_mfma(
    const unsigned short* __restrict__ A,    // [Mp,256] bf16
    const unsigned short* __restrict__ B,    // [Mp,128] bf16
    const float* __restrict__ c1,            // [Mp]
    const float* __restrict__ c2,            // [Mp]
    const unsigned short* __restrict__ WmT,  // [256,256] bf16 (N-major)
    const float* __restrict__ bm,            // [256]
    const unsigned short* __restrict__ WsT,  // [256,128] bf16 (N-major)
    const float* __restrict__ bs,            // [256]
    float* __restrict__ out,                 // [M,256]
    int M)
{
  __shared__ unsigned short lWm[64][264];    // 64 cols x 256 K, +8 pad
  __shared__ unsigned short lWs[64][136];    // 64 cols x 128 K, +8 pad

  const int tid  = (int)threadIdx.x;
  const int lane = tid & 63;
  const int wv   = tid >> 6;          // 0..7
  const int l15  = lane & 15;
  const int lg   = lane >> 4;         // 0..3
  const int m0      = blockIdx.x * 256;
  const int colBlk  = blockIdx.y * 64;

  // ---- stage weight slices into LDS ----
  for (int i = tid; i < 64 * 256 / 8; i += 512) {       // 2048 x 16B
    const int c = i >> 5, k8 = (i & 31) << 3;
    *reinterpret_cast<bf16x8*>(&lWm[c][k8]) =
        *reinterpret_cast<const bf16x8*>(WmT + (size_t)(colBlk + c) * 256 + k8);
  }
  for (int i = tid; i < 64 * 128 / 8; i += 512) {       // 1024 x 16B
    const int c = i >> 4, k8 = (i & 15) << 3;
    *reinterpret_cast<bf16x8*>(&lWs[c][k8]) =
        *reinterpret_cast<const bf16x8*>(WsT + (size_t)(colBlk + c) * 128 + k8);
  }
  __syncthreads();

  const int rowA = m0 + wv * 32 + l15;

  f32x4 accM[2][4];
  f32x4 accS[2][4];
#pragma unroll
  for (int ms = 0; ms < 2; ++ms)
#pragma unroll
    for (int n = 0; n < 4; ++n) {
      accM[ms][n] = (f32x4)0.f;
      accS[ms][n] = (f32x4)0.f;
    }

  // ---- accM = A @ Wm, K = 256 ----
#pragma unroll
  for (int kc = 0; kc < 256; kc += 32) {
    const int ko = kc + lg * 8;
    const bf16x8 a0 = *reinterpret_cast<const bf16x8*>(A + (size_t)rowA * 256 + ko);
    const bf16x8 a1 = *reinterpret_cast<const bf16x8*>(A + (size_t)(rowA + 16) * 256 + ko);
#pragma unroll
    for (int n = 0; n < 4; ++n) {
      const bf16x8 w = *reinterpret_cast<const bf16x8*>(&lWm[l15 + n * 16][ko]);
      accM[0][n] = __builtin_amdgcn_mfma_f32_16x16x32_bf16(a0, w, accM[0][n], 0, 0, 0);
      accM[1][n] = __builtin_amdgcn_mfma_f32_16x16x32_bf16(a1, w, accM[1][n], 0, 0, 0);
    }
  }

  // ---- accS = B @ Ws, K = 128 ----
#pragma unroll
  for (int kc = 0; kc < 128; kc += 32) {
    const int ko = kc + lg * 8;
    const bf16x8 b0 = *reinterpret_cast<const bf16x8*>(B + (size_t)rowA * 128 + ko);
    const bf16x8 b1 = *reinterpret_cast<const bf16x8*>(B + (size_t)(rowA + 16) * 128 + ko);
#pragma unroll
    for (int n = 0; n < 4; ++n) {
      const bf16x8 w = *reinterpret_cast<const bf16x8*>(&lWs[l15 + n * 16][ko]);
      accS[0][n] = __builtin_amdgcn_mfma_f32_16x16x32_bf16(b0, w, accS[0][n], 0, 0, 0);
      accS[1][n] = __builtin_amdgcn_mfma_f32_16x16x32_bf16(b1, w, accS[1][n], 0, 0, 0);
    }
  }

  // ---- epilogue: (accM + c1*bm) .* (accS + c2*bs) ----
  float bmv[4], bsv[4];
#pragma unroll
  for (int n = 0; n < 4; ++n) {
    bmv[n] = bm[colBlk + n * 16 + l15];
    bsv[n] = bs[colBlk + n * 16 + l15];
  }
#pragma unroll
  for (int ms = 0; ms < 2; ++ms) {
    const int rbase = m0 + wv * 32 + ms * 16 + lg * 4;
#pragma unroll
    for (int r = 0; r < 4; ++r) {
      const int row = rbase + r;
      if (row < M) {
        const float k1 = c1[row];
        const float k2 = c2[row];
#pragma unroll
        for (int n = 0; n < 4; ++n) {
          const int col = colBlk + n * 16 + l15;
          const float mv = accM[ms][n][r] + k1 * bmv[n];
          const float sv = accS[ms][n][r] + k2 * bsv[n];
          out[(size_t)row * 256 + col] = mv * sv;
        }
      }
    }
  }
}

extern "C" void kernel_launch(void* const* d_in, const int* in_sizes, int n_in,
                              void* d_out, int out_size, void* d_ws, size_t ws_size,
                              hipStream_t stream) {
  const float* node_features  = (const float*)d_in[0];   // [50000,256]
  const float* hedge_features = (const float*)d_in[1];   // [25000,128]
  const int*   node_senders   = (const int*)d_in[2];     // [E]
  const int*   node_receivers = (const int*)d_in[3];     // [E] sorted
  const float* node_conv      = (const float*)d_in[4];   // [E]
  const int*   h2n_senders    = (const int*)d_in[5];     // [E2]
  const int*   h2n_receivers  = (const int*)d_in[6];     // [E2] sorted
  const float* h2n_conv       = (const float*)d_in[7];   // [E2]
  const float* Wm             = (const float*)d_in[8];   // [256,256]
  const float* bm             = (const float*)d_in[9];   // [256]
  const float* Ws             = (const float*)d_in[10];  // [128,256]
  const float* bs             = (const float*)d_in[11];  // [256]
  float* out = (float*)d_out;

  const int M   = in_sizes[0] / 256;       // 50000 nodes
  const int Nh  = in_sizes[1] / 128;       // 25000 hedges
  const int E   = in_sizes[2];             // 800000
  const int E2  = in_sizes[5];             // 400000
  const int Mp  = ((M + 255) / 256) * 256; // padded rows for 256-row GEMM tiles

  // Workspace layout (bf16 = unsigned short):
  //   A[Mp,256] | B[Mp,128] | Xs[8][M][32] | Hs[2][Nh][64]
  //   | WmT[256,256] | WsT[256,128] | c1 f32[Mp] | c2 f32[Mp] | ro1 | ro2
  unsigned short* Ab  = (unsigned short*)d_ws;
  unsigned short* Bb  = Ab + (size_t)Mp * 256;
  unsigned short* Xs  = Bb + (size_t)Mp * 128;
  unsigned short* Hs  = Xs + (size_t)M * 256;
  unsigned short* WmT = Hs + (size_t)Nh * 128;
  unsigned short* WsT = WmT + 256 * 256;
  float* c1 = (float*)(WsT + 256 * 128);
  float* c2 = c1 + Mp;
  int*   ro1 = (int*)(c2 + Mp);
  int*   ro2 = ro1 + (M + 1);

  const int nX4 = M * 256 / 4, nH4 = Nh * 128 / 4;
  const int bX  = (nX4 + 255) / 256;
  const int bH  = (nH4 + 255) / 256;
  const int bE1 = (E + 255) / 256;
  const int bE2 = (E2 + 255) / 256;
  const int prep_blocks = bX + bH + bE1 + bE2 + 64 + 32;

  prep_all<<<prep_blocks, 256, 0, stream>>>(
      node_features, hedge_features,
      node_receivers, E, h2n_receivers, E2, M, Nh,
      Wm, Ws, Xs, Hs, ro1, ro2, WmT, WsT, nX4, nH4);

  // Persistent grid-stride scatters: 8 slices x 1024 blocks (node),
  // 2 slices x 1024 blocks (hedge). slice = bid % nslices -> XCD-pinned.
  scatter_node_slice<<<8 * 1024, 256, 0, stream>>>(
      Xs, node_senders, node_conv, ro1, Ab, c1, M);
  scatter_hedge_slice<<<2 * 1024, 256, 0, stream>>>(
      Hs, h2n_senders, h2n_conv, ro2, Bb, c2, M, Nh);

  gemm_combine_mfma<<<dim3(Mp / 256, 4), 512, 0, stream>>>(
      Ab, Bb, c1, c2, WmT, bm, WsT, bs, out, M);
}

// Round 9
// 136.834 us; speedup vs baseline: 1.6382x; 1.5761x over previous
//
#include <hip/hip_runtime.h>

// ---------------------------------------------------------------------------
// Pipeline (algebraically restructured from the reference):
//   Xb = bf16(node_features), Hb = bf16(hedge_features)     (prep_all)
//   A[n,:]  = sum_{e: rcv=n} conv_e * Xb[snd_e,:]           (f32 acc -> bf16)
//   c1[n]   = sum_{e: rcv=n} conv_e
//   B[n,:]  = sum_{e2} conv2_e * Hb[snd_e,:]                (f32 acc -> bf16)
//   c2[n]   = sum conv2_e
//   out     = (A@Wm + c1*bm) .* (B@Ws + c2*bs)   -- bf16 MFMA, f32 accum
//
// Best-of-rounds config: R5/R6 fused prep + R4 scatter schedule (one wave
// per node, deep-unrolled full-row gathers; slicing abandoned after R6-R8
// showed its task overhead exceeds the fabric savings) + R5 LDS-weight GEMM.
// ---------------------------------------------------------------------------

typedef __attribute__((ext_vector_type(8))) short bf16x8;
typedef __attribute__((ext_vector_type(4))) float f32x4;

static __device__ __forceinline__ unsigned short f2bf(float f) {
  unsigned u = __float_as_uint(f);
  u += 0x7fff + ((u >> 16) & 1);          // round-to-nearest-even
  return (unsigned short)(u >> 16);
}
static __device__ __forceinline__ float bf2f(unsigned short h) {
  return __uint_as_float((unsigned)h << 16);
}

// ---------------------------------------------------------------------------
// prep_all: blockIdx ranges ->
//   [0,bX)     : cvt X f32 -> Xb bf16
//   [bX,+bH)   : cvt H f32 -> Hb bf16
//   [..,+bE1)  : row offsets for node_receivers
//   [..,+bE2)  : row offsets for h2n_receivers
//   [..,+64)   : transpose Wm (256x256) -> WmT bf16
//   [..,+32)   : transpose Ws (128x256) -> WsT bf16
// ---------------------------------------------------------------------------
__global__ __launch_bounds__(256) void prep_all(
    const float* __restrict__ X, const float* __restrict__ H,
    const int* __restrict__ rcv1, int E1,
    const int* __restrict__ rcv2, int E2, int N,
    const float* __restrict__ Wm, const float* __restrict__ Ws,
    unsigned short* __restrict__ Xb, unsigned short* __restrict__ Hb,
    int* __restrict__ ro1, int* __restrict__ ro2,
    unsigned short* __restrict__ WmT, unsigned short* __restrict__ WsT,
    int nX4, int nH4)
{
  __shared__ float t[32][33];
  const int tid = (int)threadIdx.x;
  int b = (int)blockIdx.x;

  const int bX  = (nX4 + 255) / 256;
  const int bH  = (nH4 + 255) / 256;
  const int bE1 = (E1 + 255) / 256;
  const int bE2 = (E2 + 255) / 256;

  if (b < bX) {                       // ---- cvt X ----
    const int i = b * 256 + tid;
    if (i < nX4) {
      const float4 v = reinterpret_cast<const float4*>(X)[i];
      reinterpret_cast<ushort4*>(Xb)[i] =
          make_ushort4(f2bf(v.x), f2bf(v.y), f2bf(v.z), f2bf(v.w));
    }
    return;
  }
  b -= bX;
  if (b < bH) {                       // ---- cvt H ----
    const int i = b * 256 + tid;
    if (i < nH4) {
      const float4 v = reinterpret_cast<const float4*>(H)[i];
      reinterpret_cast<ushort4*>(Hb)[i] =
          make_ushort4(f2bf(v.x), f2bf(v.y), f2bf(v.z), f2bf(v.w));
    }
    return;
  }
  b -= bH;
  if (b < bE1) {                      // ---- row offsets 1 ----
    const int e = b * 256 + tid;
    if (e < E1) {
      const int c = rcv1[e];
      const int p = (e == 0) ? -1 : rcv1[e - 1];
      for (int n = p + 1; n <= c; ++n) ro1[n] = e;
      if (e == E1 - 1)
        for (int n = c + 1; n <= N; ++n) ro1[n] = E1;
    }
    return;
  }
  b -= bE1;
  if (b < bE2) {                      // ---- row offsets 2 ----
    const int e = b * 256 + tid;
    if (e < E2) {
      const int c = rcv2[e];
      const int p = (e == 0) ? -1 : rcv2[e - 1];
      for (int n = p + 1; n <= c; ++n) ro2[n] = e;
      if (e == E2 - 1)
        for (int n = c + 1; n <= N; ++n) ro2[n] = E2;
    }
    return;
  }
  b -= bE2;
  {
    // ---- weight transposes: Wm tiles [0,64), Ws tiles [64,96) ----
    const float* W; unsigned short* WT; int K, Nn, tile;
    if (b < 64) { W = Wm; WT = WmT; K = 256; Nn = 256; tile = b; }
    else        { W = Ws; WT = WsT; K = 128; Nn = 256; tile = b - 64; }
    const int ntiles_n = Nn / 32;
    const int n0 = (tile % ntiles_n) * 32;
    const int k0 = (tile / ntiles_n) * 32;
    const int tx = tid & 31, ty = tid >> 5;   // 32 x 8
#pragma unroll
    for (int i = 0; i < 32; i += 8)
      t[ty + i][tx] = W[(size_t)(k0 + ty + i) * Nn + n0 + tx];
    __syncthreads();
#pragma unroll
    for (int i = 0; i < 32; i += 8)
      WT[(size_t)(n0 + ty + i) * K + k0 + tx] = f2bf(t[tx][ty + i]);
  }
}

// One wave per node, C=256 bf16 channels (ushort4 per lane). No atomics.
// 16 independent gathers in flight per iteration (R4 schedule, 55.6 us).
__global__ __launch_bounds__(256) void scatter_node_seg(
    const unsigned short* __restrict__ X,   // [Nsrc,256] bf16
    const int* __restrict__ snd,
    const float* __restrict__ conv,
    const int* __restrict__ row_start,      // [N+1]
    unsigned short* __restrict__ A,         // [Mp,256] bf16
    float* __restrict__ csum,               // [Mp]
    int N)
{
  const int lane = threadIdx.x & 63;
  const int node = __builtin_amdgcn_readfirstlane(
      (int)blockIdx.x * 4 + ((int)threadIdx.x >> 6));
  if (node >= N) return;
  const int lo = row_start[node];
  const int hi = row_start[node + 1];

  const unsigned short* Xl = X + lane * 4;
  float4 acc = make_float4(0.f, 0.f, 0.f, 0.f);
  float cacc = 0.f;

  int e = lo;
  for (; e + 16 <= hi; e += 16) {
    int s[16]; float cv[16]; ushort4 x[16];
#pragma unroll
    for (int j = 0; j < 16; ++j) s[j] = snd[e + j];
#pragma unroll
    for (int j = 0; j < 16; ++j) cv[j] = conv[e + j];
#pragma unroll
    for (int j = 0; j < 16; ++j)
      x[j] = *reinterpret_cast<const ushort4*>(Xl + (size_t)s[j] * 256);
#pragma unroll
    for (int j = 0; j < 16; ++j) {
      acc.x = fmaf(cv[j], bf2f(x[j].x), acc.x);
      acc.y = fmaf(cv[j], bf2f(x[j].y), acc.y);
      acc.z = fmaf(cv[j], bf2f(x[j].z), acc.z);
      acc.w = fmaf(cv[j], bf2f(x[j].w), acc.w);
      cacc += cv[j];
    }
  }
  for (; e + 4 <= hi; e += 4) {
    int s[4]; float cv[4]; ushort4 x[4];
#pragma unroll
    for (int j = 0; j < 4; ++j) s[j] = snd[e + j];
#pragma unroll
    for (int j = 0; j < 4; ++j) cv[j] = conv[e + j];
#pragma unroll
    for (int j = 0; j < 4; ++j)
      x[j] = *reinterpret_cast<const ushort4*>(Xl + (size_t)s[j] * 256);
#pragma unroll
    for (int j = 0; j < 4; ++j) {
      acc.x = fmaf(cv[j], bf2f(x[j].x), acc.x);
      acc.y = fmaf(cv[j], bf2f(x[j].y), acc.y);
      acc.z = fmaf(cv[j], bf2f(x[j].z), acc.z);
      acc.w = fmaf(cv[j], bf2f(x[j].w), acc.w);
      cacc += cv[j];
    }
  }
  for (; e < hi; ++e) {
    const int s = snd[e];
    const float cv = conv[e];
    const ushort4 x = *reinterpret_cast<const ushort4*>(Xl + (size_t)s * 256);
    acc.x = fmaf(cv, bf2f(x.x), acc.x);
    acc.y = fmaf(cv, bf2f(x.y), acc.y);
    acc.z = fmaf(cv, bf2f(x.z), acc.z);
    acc.w = fmaf(cv, bf2f(x.w), acc.w);
    cacc += cv;
  }

  *reinterpret_cast<ushort4*>(A + (size_t)node * 256 + lane * 4) =
      make_ushort4(f2bf(acc.x), f2bf(acc.y), f2bf(acc.z), f2bf(acc.w));
  if (lane == 0) csum[node] = cacc;
}

// One wave per node, C=128 bf16 channels (ushort2 per lane). No atomics.
__global__ __launch_bounds__(256) void scatter_hedge_seg(
    const unsigned short* __restrict__ X,   // [Nsrc,128] bf16
    const int* __restrict__ snd,
    const float* __restrict__ conv,
    const int* __restrict__ row_start,      // [N+1]
    unsigned short* __restrict__ B,         // [Mp,128] bf16
    float* __restrict__ csum,               // [Mp]
    int N)
{
  const int lane = threadIdx.x & 63;
  const int node = __builtin_amdgcn_readfirstlane(
      (int)blockIdx.x * 4 + ((int)threadIdx.x >> 6));
  if (node >= N) return;
  const int lo = row_start[node];
  const int hi = row_start[node + 1];

  const unsigned short* Xl = X + lane * 2;
  float2 acc = make_float2(0.f, 0.f);
  float cacc = 0.f;

  int e = lo;
  for (; e + 8 <= hi; e += 8) {
    int s[8]; float cv[8]; ushort2 x[8];
#pragma unroll
    for (int j = 0; j < 8; ++j) s[j] = snd[e + j];
#pragma unroll
    for (int j = 0; j < 8; ++j) cv[j] = conv[e + j];
#pragma unroll
    for (int j = 0; j < 8; ++j)
      x[j] = *reinterpret_cast<const ushort2*>(Xl + (size_t)s[j] * 128);
#pragma unroll
    for (int j = 0; j < 8; ++j) {
      acc.x = fmaf(cv[j], bf2f(x[j].x), acc.x);
      acc.y = fmaf(cv[j], bf2f(x[j].y), acc.y);
      cacc += cv[j];
    }
  }
  for (; e < hi; ++e) {
    const int s = snd[e];
    const float cv = conv[e];
    const ushort2 x = *reinterpret_cast<const ushort2*>(Xl + (size_t)s * 128);
    acc.x = fmaf(cv, bf2f(x.x), acc.x);
    acc.y = fmaf(cv, bf2f(x.y), acc.y);
    cacc += cv;
  }

  *reinterpret_cast<ushort2*>(B + (size_t)node * 128 + lane * 2) =
      make_ushort2(f2bf(acc.x), f2bf(acc.y));
  if (lane == 0) csum[node] = cacc;
}

// ---------------------------------------------------------------------------
// MFMA dual-GEMM + bias + Hadamard, LDS-cached weight slice.
// Grid: (Mp/256, 4). Block = 512 threads = 8 waves; block tile 256 rows x
// 64 cols. Wave owns 32 rows x 64 cols (2 m-sub x 4 n-sub of 16x16).
// mfma_f32_16x16x32_bf16 fragments:
//   A-frag: row = lane&15, k = 8*(lane>>4) + j
//   B-frag: col = lane&15, k = 8*(lane>>4) + j
//   C/D   : col = lane&15, row = 4*(lane>>4) + reg   [m89-verified]
// ---------------------------------------------------------------------------
__global__ __launch_bounds__(512) void gemm_combine_mfma(
    const unsigned short* __restrict__ A,    // [Mp,256] bf16
    const unsigned short* __restrict__ B,    // [Mp,128] bf16
    const float* __restrict__ c1,            // [Mp]
    const float* __restrict__ c2,            // [Mp]
    const unsigned short* __restrict__ WmT,  // [256,256] bf16 (N-major)
    const float* __restrict__ bm,            // [256]
    const unsigned short* __restrict__ WsT,  // [256,128] bf16 (N-major)
    const float* __restrict__ bs,            // [256]
    float* __restrict__ out,                 // [M,256]
    int M)
{
  __shared__ unsigned short lWm[64][264];    // 64 cols x 256 K, +8 pad
  __shared__ unsigned short lWs[64][136];    // 64 cols x 128 K, +8 pad

  const int tid  = (int)threadIdx.x;
  const int lane = tid & 63;
  const int wv   = tid >> 6;          // 0..7
  const int l15  = lane & 15;
  const int lg   = lane >> 4;         // 0..3
  const int m0      = blockIdx.x * 256;
  const int colBlk  = blockIdx.y * 64;

  // ---- stage weight slices into LDS ----
  for (int i = tid; i < 64 * 256 / 8; i += 512) {       // 2048 x 16B
    const int c = i >> 5, k8 = (i & 31) << 3;
    *reinterpret_cast<bf16x8*>(&lWm[c][k8]) =
        *reinterpret_cast<const bf16x8*>(WmT + (size_t)(colBlk + c) * 256 + k8);
  }
  for (int i = tid; i < 64 * 128 / 8; i += 512) {       // 1024 x 16B
    const int c = i >> 4, k8 = (i & 15) << 3;
    *reinterpret_cast<bf16x8*>(&lWs[c][k8]) =
        *reinterpret_cast<const bf16x8*>(WsT + (size_t)(colBlk + c) * 128 + k8);
  }
  __syncthreads();

  const int rowA = m0 + wv * 32 + l15;

  f32x4 accM[2][4];
  f32x4 accS[2][4];
#pragma unroll
  for (int ms = 0; ms < 2; ++ms)
#pragma unroll
    for (int n = 0; n < 4; ++n) {
      accM[ms][n] = (f32x4)0.f;
      accS[ms][n] = (f32x4)0.f;
    }

  // ---- accM = A @ Wm, K = 256 ----
#pragma unroll
  for (int kc = 0; kc < 256; kc += 32) {
    const int ko = kc + lg * 8;
    const bf16x8 a0 = *reinterpret_cast<const bf16x8*>(A + (size_t)rowA * 256 + ko);
    const bf16x8 a1 = *reinterpret_cast<const bf16x8*>(A + (size_t)(rowA + 16) * 256 + ko);
#pragma unroll
    for (int n = 0; n < 4; ++n) {
      const bf16x8 w = *reinterpret_cast<const bf16x8*>(&lWm[l15 + n * 16][ko]);
      accM[0][n] = __builtin_amdgcn_mfma_f32_16x16x32_bf16(a0, w, accM[0][n], 0, 0, 0);
      accM[1][n] = __builtin_amdgcn_mfma_f32_16x16x32_bf16(a1, w, accM[1][n], 0, 0, 0);
    }
  }

  // ---- accS = B @ Ws, K = 128 ----
#pragma unroll
  for (int kc = 0; kc < 128; kc += 32) {
    const int ko = kc + lg * 8;
    const bf16x8 b0 = *reinterpret_cast<const bf16x8*>(B + (size_t)rowA * 128 + ko);
    const bf16x8 b1 = *reinterpret_cast<const bf16x8*>(B + (size_t)(rowA + 16) * 128 + ko);
#pragma unroll
    for (int n = 0; n < 4; ++n) {
      const bf16x8 w = *reinterpret_cast<const bf16x8*>(&lWs[l15 + n * 16][ko]);
      accS[0][n] = __builtin_amdgcn_mfma_f32_16x16x32_bf16(b0, w, accS[0][n], 0, 0, 0);
      accS[1][n] = __builtin_amdgcn_mfma_f32_16x16x32_bf16(b1, w, accS[1][n], 0, 0, 0);
    }
  }

  // ---- epilogue: (accM + c1*bm) .* (accS + c2*bs) ----
  float bmv[4], bsv[4];
#pragma unroll
  for (int n = 0; n < 4; ++n) {
    bmv[n] = bm[colBlk + n * 16 + l15];
    bsv[n] = bs[colBlk + n * 16 + l15];
  }
#pragma unroll
  for (int ms = 0; ms < 2; ++ms) {
    const int rbase = m0 + wv * 32 + ms * 16 + lg * 4;
#pragma unroll
    for (int r = 0; r < 4; ++r) {
      const int row = rbase + r;
      if (row < M) {
        const float k1 = c1[row];
        const float k2 = c2[row];
#pragma unroll
        for (int n = 0; n < 4; ++n) {
          const int col = colBlk + n * 16 + l15;
          const float mv = accM[ms][n][r] + k1 * bmv[n];
          const float sv = accS[ms][n][r] + k2 * bsv[n];
          out[(size_t)row * 256 + col] = mv * sv;
        }
      }
    }
  }
}

extern "C" void kernel_launch(void* const* d_in, const int* in_sizes, int n_in,
                              void* d_out, int out_size, void* d_ws, size_t ws_size,
                              hipStream_t stream) {
  const float* node_features  = (const float*)d_in[0];   // [50000,256]
  const float* hedge_features = (const float*)d_in[1];   // [25000,128]
  const int*   node_senders   = (const int*)d_in[2];     // [E]
  const int*   node_receivers = (const int*)d_in[3];     // [E] sorted
  const float* node_conv      = (const float*)d_in[4];   // [E]
  const int*   h2n_senders    = (const int*)d_in[5];     // [E2]
  const int*   h2n_receivers  = (const int*)d_in[6];     // [E2] sorted
  const float* h2n_conv       = (const float*)d_in[7];   // [E2]
  const float* Wm             = (const float*)d_in[8];   // [256,256]
  const float* bm             = (const float*)d_in[9];   // [256]
  const float* Ws             = (const float*)d_in[10];  // [128,256]
  const float* bs             = (const float*)d_in[11];  // [256]
  float* out = (float*)d_out;

  const int M   = in_sizes[0] / 256;       // 50000 nodes
  const int Nh  = in_sizes[1] / 128;       // 25000 hedges
  const int E   = in_sizes[2];             // 800000
  const int E2  = in_sizes[5];             // 400000
  const int Mp  = ((M + 255) / 256) * 256; // padded rows for 256-row GEMM tiles

  // Workspace layout (bf16 = unsigned short):
  //   A[Mp,256] | B[Mp,128] | Xb[M,256] | Hb[Nh,128] | WmT[256,256]
  //   | WsT[256,128] | c1 f32[Mp] | c2 f32[Mp] | ro1 [M+1] | ro2 [M+1]
  unsigned short* Ab  = (unsigned short*)d_ws;
  unsigned short* Bb  = Ab + (size_t)Mp * 256;
  unsigned short* Xb  = Bb + (size_t)Mp * 128;
  unsigned short* Hb  = Xb + (size_t)M * 256;
  unsigned short* WmT = Hb + (size_t)Nh * 128;
  unsigned short* WsT = WmT + 256 * 256;
  float* c1 = (float*)(WsT + 256 * 128);
  float* c2 = c1 + Mp;
  int*   ro1 = (int*)(c2 + Mp);
  int*   ro2 = ro1 + (M + 1);

  const int nX4 = M * 256 / 4, nH4 = Nh * 128 / 4;
  const int bX  = (nX4 + 255) / 256;
  const int bH  = (nH4 + 255) / 256;
  const int bE1 = (E + 255) / 256;
  const int bE2 = (E2 + 255) / 256;
  const int prep_blocks = bX + bH + bE1 + bE2 + 64 + 32;

  prep_all<<<prep_blocks, 256, 0, stream>>>(
      node_features, hedge_features,
      node_receivers, E, h2n_receivers, E2, M,
      Wm, Ws, Xb, Hb, ro1, ro2, WmT, WsT, nX4, nH4);

  // One wave per node: 4 waves per block (R4 schedule).
  scatter_node_seg<<<(M + 3) / 4, 256, 0, stream>>>(
      Xb, node_senders, node_conv, ro1, Ab, c1, M);
  scatter_hedge_seg<<<(M + 3) / 4, 256, 0, stream>>>(
      Hb, h2n_senders, h2n_conv, ro2, Bb, c2, M);

  gemm_combine_mfma<<<dim3(Mp / 256, 4), 512, 0, stream>>>(
      Ab, Bb, c1, c2, WmT, bm, WsT, bs, out, M);
}

// Round 10
// 123.826 us; speedup vs baseline: 1.8103x; 1.1050x over previous
//
#include <hip/hip_runtime.h>

// ---------------------------------------------------------------------------
// Pipeline (algebraically restructured from the reference):
//   Xb = bf16(node_features), Hb = bf16(hedge_features)     (prep_all)
//   A[n,:]  = sum_{e: rcv=n} conv_e * Xb[snd_e,:]           (f32 acc -> bf16)
//   c1[n]   = sum_{e: rcv=n} conv_e
//   B[n,:]  = sum_{e2} conv2_e * Hb[snd_e,:]                (f32 acc -> bf16)
//   c2[n]   = sum conv2_e
//   out     = (A@Wm + c1*bm) .* (B@Ws + c2*bs)   -- bf16 MFMA, f32 accum
//
// R10: scatters use masked full-width chunks (E[serial latency batches/node]
// 4 -> 1.4); GEMM holds A/B fragments in VGPR and loops col-blocks internally
// (A/B read once instead of 4x).
// ---------------------------------------------------------------------------

typedef __attribute__((ext_vector_type(8))) short bf16x8;
typedef __attribute__((ext_vector_type(4))) float f32x4;

static __device__ __forceinline__ unsigned short f2bf(float f) {
  unsigned u = __float_as_uint(f);
  u += 0x7fff + ((u >> 16) & 1);          // round-to-nearest-even
  return (unsigned short)(u >> 16);
}
static __device__ __forceinline__ float bf2f(unsigned short h) {
  return __uint_as_float((unsigned)h << 16);
}

// ---------------------------------------------------------------------------
// prep_all: blockIdx ranges ->
//   [0,bX)     : cvt X f32 -> Xb bf16
//   [bX,+bH)   : cvt H f32 -> Hb bf16
//   [..,+bE1)  : row offsets for node_receivers
//   [..,+bE2)  : row offsets for h2n_receivers
//   [..,+64)   : transpose Wm (256x256) -> WmT bf16
//   [..,+32)   : transpose Ws (128x256) -> WsT bf16
// ---------------------------------------------------------------------------
__global__ __launch_bounds__(256) void prep_all(
    const float* __restrict__ X, const float* __restrict__ H,
    const int* __restrict__ rcv1, int E1,
    const int* __restrict__ rcv2, int E2, int N,
    const float* __restrict__ Wm, const float* __restrict__ Ws,
    unsigned short* __restrict__ Xb, unsigned short* __restrict__ Hb,
    int* __restrict__ ro1, int* __restrict__ ro2,
    unsigned short* __restrict__ WmT, unsigned short* __restrict__ WsT,
    int nX4, int nH4)
{
  __shared__ float t[32][33];
  const int tid = (int)threadIdx.x;
  int b = (int)blockIdx.x;

  const int bX  = (nX4 + 255) / 256;
  const int bH  = (nH4 + 255) / 256;
  const int bE1 = (E1 + 255) / 256;
  const int bE2 = (E2 + 255) / 256;

  if (b < bX) {                       // ---- cvt X ----
    const int i = b * 256 + tid;
    if (i < nX4) {
      const float4 v = reinterpret_cast<const float4*>(X)[i];
      reinterpret_cast<ushort4*>(Xb)[i] =
          make_ushort4(f2bf(v.x), f2bf(v.y), f2bf(v.z), f2bf(v.w));
    }
    return;
  }
  b -= bX;
  if (b < bH) {                       // ---- cvt H ----
    const int i = b * 256 + tid;
    if (i < nH4) {
      const float4 v = reinterpret_cast<const float4*>(H)[i];
      reinterpret_cast<ushort4*>(Hb)[i] =
          make_ushort4(f2bf(v.x), f2bf(v.y), f2bf(v.z), f2bf(v.w));
    }
    return;
  }
  b -= bH;
  if (b < bE1) {                      // ---- row offsets 1 ----
    const int e = b * 256 + tid;
    if (e < E1) {
      const int c = rcv1[e];
      const int p = (e == 0) ? -1 : rcv1[e - 1];
      for (int n = p + 1; n <= c; ++n) ro1[n] = e;
      if (e == E1 - 1)
        for (int n = c + 1; n <= N; ++n) ro1[n] = E1;
    }
    return;
  }
  b -= bE1;
  if (b < bE2) {                      // ---- row offsets 2 ----
    const int e = b * 256 + tid;
    if (e < E2) {
      const int c = rcv2[e];
      const int p = (e == 0) ? -1 : rcv2[e - 1];
      for (int n = p + 1; n <= c; ++n) ro2[n] = e;
      if (e == E2 - 1)
        for (int n = c + 1; n <= N; ++n) ro2[n] = E2;
    }
    return;
  }
  b -= bE2;
  {
    // ---- weight transposes: Wm tiles [0,64), Ws tiles [64,96) ----
    const float* W; unsigned short* WT; int K, Nn, tile;
    if (b < 64) { W = Wm; WT = WmT; K = 256; Nn = 256; tile = b; }
    else        { W = Ws; WT = WsT; K = 128; Nn = 256; tile = b - 64; }
    const int ntiles_n = Nn / 32;
    const int n0 = (tile % ntiles_n) * 32;
    const int k0 = (tile / ntiles_n) * 32;
    const int tx = tid & 31, ty = tid >> 5;   // 32 x 8
#pragma unroll
    for (int i = 0; i < 32; i += 8)
      t[ty + i][tx] = W[(size_t)(k0 + ty + i) * Nn + n0 + tx];
    __syncthreads();
#pragma unroll
    for (int i = 0; i < 32; i += 8)
      WT[(size_t)(n0 + ty + i) * K + k0 + tx] = f2bf(t[tx][ty + i]);
  }
}

// One wave per node, C=256 bf16 channels (ushort4 per lane). No atomics.
// Masked full-16 chunks: every chunk issues 16 gathers (tail edges clamped
// to hi-1 with conv=0) so the per-node serial latency chain is ceil(d/16)
// batches instead of ~4 (16/4/1 mixed tails).
__global__ __launch_bounds__(256) void scatter_node_seg(
    const unsigned short* __restrict__ X,   // [Nsrc,256] bf16
    const int* __restrict__ snd,
    const float* __restrict__ conv,
    const int* __restrict__ row_start,      // [N+1]
    unsigned short* __restrict__ A,         // [Mp,256] bf16
    float* __restrict__ csum,               // [Mp]
    int N)
{
  const int lane = threadIdx.x & 63;
  const int node = __builtin_amdgcn_readfirstlane(
      (int)blockIdx.x * 4 + ((int)threadIdx.x >> 6));
  if (node >= N) return;
  const int lo = row_start[node];
  const int hi = row_start[node + 1];

  const unsigned short* Xl = X + lane * 4;
  float4 acc = make_float4(0.f, 0.f, 0.f, 0.f);
  float cacc = 0.f;

  for (int e = lo; e < hi; e += 16) {
    int s[16]; float cv[16]; ushort4 x[16];
#pragma unroll
    for (int j = 0; j < 16; ++j) {
      const int idx = e + j;
      const int ic = idx < hi ? idx : hi - 1;
      s[j]  = snd[ic];
      cv[j] = idx < hi ? conv[ic] : 0.f;
    }
#pragma unroll
    for (int j = 0; j < 16; ++j)
      x[j] = *reinterpret_cast<const ushort4*>(Xl + (size_t)s[j] * 256);
#pragma unroll
    for (int j = 0; j < 16; ++j) {
      acc.x = fmaf(cv[j], bf2f(x[j].x), acc.x);
      acc.y = fmaf(cv[j], bf2f(x[j].y), acc.y);
      acc.z = fmaf(cv[j], bf2f(x[j].z), acc.z);
      acc.w = fmaf(cv[j], bf2f(x[j].w), acc.w);
      cacc += cv[j];
    }
  }

  *reinterpret_cast<ushort4*>(A + (size_t)node * 256 + lane * 4) =
      make_ushort4(f2bf(acc.x), f2bf(acc.y), f2bf(acc.z), f2bf(acc.w));
  if (lane == 0) csum[node] = cacc;
}

// One wave per node, C=128 bf16 channels (ushort2 per lane). No atomics.
// Masked full-16 chunks (Poisson(8) degree -> ~1.2 batches/node).
__global__ __launch_bounds__(256) void scatter_hedge_seg(
    const unsigned short* __restrict__ X,   // [Nsrc,128] bf16
    const int* __restrict__ snd,
    const float* __restrict__ conv,
    const int* __restrict__ row_start,      // [N+1]
    unsigned short* __restrict__ B,         // [Mp,128] bf16
    float* __restrict__ csum,               // [Mp]
    int N)
{
  const int lane = threadIdx.x & 63;
  const int node = __builtin_amdgcn_readfirstlane(
      (int)blockIdx.x * 4 + ((int)threadIdx.x >> 6));
  if (node >= N) return;
  const int lo = row_start[node];
  const int hi = row_start[node + 1];

  const unsigned short* Xl = X + lane * 2;
  float2 acc = make_float2(0.f, 0.f);
  float cacc = 0.f;

  for (int e = lo; e < hi; e += 16) {
    int s[16]; float cv[16]; ushort2 x[16];
#pragma unroll
    for (int j = 0; j < 16; ++j) {
      const int idx = e + j;
      const int ic = idx < hi ? idx : hi - 1;
      s[j]  = snd[ic];
      cv[j] = idx < hi ? conv[ic] : 0.f;
    }
#pragma unroll
    for (int j = 0; j < 16; ++j)
      x[j] = *reinterpret_cast<const ushort2*>(Xl + (size_t)s[j] * 128);
#pragma unroll
    for (int j = 0; j < 16; ++j) {
      acc.x = fmaf(cv[j], bf2f(x[j].x), acc.x);
      acc.y = fmaf(cv[j], bf2f(x[j].y), acc.y);
      cacc += cv[j];
    }
  }

  *reinterpret_cast<ushort2*>(B + (size_t)node * 128 + lane * 2) =
      make_ushort2(f2bf(acc.x), f2bf(acc.y));
  if (lane == 0) csum[node] = cacc;
}

// ---------------------------------------------------------------------------
// MFMA dual-GEMM + bias + Hadamard, A/B-resident version.
// Grid: Mp/256 blocks of 512 threads (8 waves). Each block owns a 256-row
// tile; A/B fragments for the whole K are loaded ONCE into VGPRs, then the
// block loops over 4 col-blocks of 64, staging that W slice in LDS.
// A/B global traffic: 1x (was 4x with grid.y=4 col-blocks).
// mfma_f32_16x16x32_bf16 fragments:
//   A-frag: row = lane&15, k = 8*(lane>>4) + j
//   B-frag: col = lane&15, k = 8*(lane>>4) + j
//   C/D   : col = lane&15, row = 4*(lane>>4) + reg   [m89-verified]
// ---------------------------------------------------------------------------
__global__ __launch_bounds__(512) void gemm_combine_mfma(
    const unsigned short* __restrict__ A,    // [Mp,256] bf16
    const unsigned short* __restrict__ B,    // [Mp,128] bf16
    const float* __restrict__ c1,            // [Mp]
    const float* __restrict__ c2,            // [Mp]
    const unsigned short* __restrict__ WmT,  // [256,256] bf16 (N-major)
    const float* __restrict__ bm,            // [256]
    const unsigned short* __restrict__ WsT,  // [256,128] bf16 (N-major)
    const float* __restrict__ bs,            // [256]
    float* __restrict__ out,                 // [M,256]
    int M)
{
  __shared__ unsigned short lWm[64][264];    // 64 cols x 256 K, +8 pad
  __shared__ unsigned short lWs[64][136];    // 64 cols x 128 K, +8 pad

  const int tid  = (int)threadIdx.x;
  const int lane = tid & 63;
  const int wv   = tid >> 6;          // 0..7
  const int l15  = lane & 15;
  const int lg   = lane >> 4;         // 0..3
  const int m0   = blockIdx.x * 256;

  const int rowA = m0 + wv * 32 + l15;

  // ---- load A/B fragments for the whole K once (held in VGPRs) ----
  bf16x8 afrag[2][8];
  bf16x8 bfrag[2][4];
#pragma unroll
  for (int k8 = 0; k8 < 8; ++k8) {
    const int ko = k8 * 32 + lg * 8;
    afrag[0][k8] = *reinterpret_cast<const bf16x8*>(A + (size_t)rowA * 256 + ko);
    afrag[1][k8] = *reinterpret_cast<const bf16x8*>(A + (size_t)(rowA + 16) * 256 + ko);
  }
#pragma unroll
  for (int k8 = 0; k8 < 4; ++k8) {
    const int ko = k8 * 32 + lg * 8;
    bfrag[0][k8] = *reinterpret_cast<const bf16x8*>(B + (size_t)rowA * 128 + ko);
    bfrag[1][k8] = *reinterpret_cast<const bf16x8*>(B + (size_t)(rowA + 16) * 128 + ko);
  }

  // ---- per-row conv sums for the bias terms (rows this lane stores) ----
  float k1v[2][4], k2v[2][4];
#pragma unroll
  for (int ms = 0; ms < 2; ++ms)
#pragma unroll
    for (int r = 0; r < 4; ++r) {
      const int row = m0 + wv * 32 + ms * 16 + lg * 4 + r;
      const bool v = row < M;
      k1v[ms][r] = v ? c1[row] : 0.f;
      k2v[ms][r] = v ? c2[row] : 0.f;
    }

  // ---- loop over 4 col-blocks of 64 ----
  for (int cb = 0; cb < 4; ++cb) {
    const int colBlk = cb * 64;
    __syncthreads();                         // LDS safe to overwrite
#pragma unroll
    for (int i = 0; i < 4; ++i) {            // lWm: 2048 x 16B
      const int idx = tid + i * 512;
      const int c = idx >> 5, k8b = (idx & 31) << 3;
      *reinterpret_cast<bf16x8*>(&lWm[c][k8b]) =
          *reinterpret_cast<const bf16x8*>(WmT + (size_t)(colBlk + c) * 256 + k8b);
    }
#pragma unroll
    for (int i = 0; i < 2; ++i) {            // lWs: 1024 x 16B
      const int idx = tid + i * 512;
      const int c = idx >> 4, k8b = (idx & 15) << 3;
      *reinterpret_cast<bf16x8*>(&lWs[c][k8b]) =
          *reinterpret_cast<const bf16x8*>(WsT + (size_t)(colBlk + c) * 128 + k8b);
    }
    __syncthreads();

    f32x4 accM[2][4];
    f32x4 accS[2][4];
#pragma unroll
    for (int ms = 0; ms < 2; ++ms)
#pragma unroll
      for (int n = 0; n < 4; ++n) {
        accM[ms][n] = (f32x4)0.f;
        accS[ms][n] = (f32x4)0.f;
      }

#pragma unroll
    for (int k8 = 0; k8 < 8; ++k8) {
      const int ko = k8 * 32 + lg * 8;
#pragma unroll
      for (int n = 0; n < 4; ++n) {
        const bf16x8 w = *reinterpret_cast<const bf16x8*>(&lWm[l15 + n * 16][ko]);
        accM[0][n] = __builtin_amdgcn_mfma_f32_16x16x32_bf16(afrag[0][k8], w, accM[0][n], 0, 0, 0);
        accM[1][n] = __builtin_amdgcn_mfma_f32_16x16x32_bf16(afrag[1][k8], w, accM[1][n], 0, 0, 0);
      }
    }
#pragma unroll
    for (int k8 = 0; k8 < 4; ++k8) {
      const int ko = k8 * 32 + lg * 8;
#pragma unroll
      for (int n = 0; n < 4; ++n) {
        const bf16x8 w = *reinterpret_cast<const bf16x8*>(&lWs[l15 + n * 16][ko]);
        accS[0][n] = __builtin_amdgcn_mfma_f32_16x16x32_bf16(bfrag[0][k8], w, accS[0][n], 0, 0, 0);
        accS[1][n] = __builtin_amdgcn_mfma_f32_16x16x32_bf16(bfrag[1][k8], w, accS[1][n], 0, 0, 0);
      }
    }

    // ---- epilogue for this col-block ----
    float bmv[4], bsv[4];
#pragma unroll
    for (int n = 0; n < 4; ++n) {
      bmv[n] = bm[colBlk + n * 16 + l15];
      bsv[n] = bs[colBlk + n * 16 + l15];
    }
#pragma unroll
    for (int ms = 0; ms < 2; ++ms) {
      const int rbase = m0 + wv * 32 + ms * 16 + lg * 4;
#pragma unroll
      for (int r = 0; r < 4; ++r) {
        const int row = rbase + r;
        if (row < M) {
#pragma unroll
          for (int n = 0; n < 4; ++n) {
            const int col = colBlk + n * 16 + l15;
            const float mv = accM[ms][n][r] + k1v[ms][r] * bmv[n];
            const float sv = accS[ms][n][r] + k2v[ms][r] * bsv[n];
            out[(size_t)row * 256 + col] = mv * sv;
          }
        }
      }
    }
  }
}

extern "C" void kernel_launch(void* const* d_in, const int* in_sizes, int n_in,
                              void* d_out, int out_size, void* d_ws, size_t ws_size,
                              hipStream_t stream) {
  const float* node_features  = (const float*)d_in[0];   // [50000,256]
  const float* hedge_features = (const float*)d_in[1];   // [25000,128]
  const int*   node_senders   = (const int*)d_in[2];     // [E]
  const int*   node_receivers = (const int*)d_in[3];     // [E] sorted
  const float* node_conv      = (const float*)d_in[4];   // [E]
  const int*   h2n_senders    = (const int*)d_in[5];     // [E2]
  const int*   h2n_receivers  = (const int*)d_in[6];     // [E2] sorted
  const float* h2n_conv       = (const float*)d_in[7];   // [E2]
  const float* Wm             = (const float*)d_in[8];   // [256,256]
  const float* bm             = (const float*)d_in[9];   // [256]
  const float* Ws             = (const float*)d_in[10];  // [128,256]
  const float* bs             = (const float*)d_in[11];  // [256]
  float* out = (float*)d_out;

  const int M   = in_sizes[0] / 256;       // 50000 nodes
  const int Nh  = in_sizes[1] / 128;       // 25000 hedges
  const int E   = in_sizes[2];             // 800000
  const int E2  = in_sizes[5];             // 400000
  const int Mp  = ((M + 255) / 256) * 256; // padded rows for 256-row GEMM tiles

  // Workspace layout (bf16 = unsigned short):
  //   A[Mp,256] | B[Mp,128] | Xb[M,256] | Hb[Nh,128] | WmT[256,256]
  //   | WsT[256,128] | c1 f32[Mp] | c2 f32[Mp] | ro1 [M+1] | ro2 [M+1]
  unsigned short* Ab  = (unsigned short*)d_ws;
  unsigned short* Bb  = Ab + (size_t)Mp * 256;
  unsigned short* Xb  = Bb + (size_t)Mp * 128;
  unsigned short* Hb  = Xb + (size_t)M * 256;
  unsigned short* WmT = Hb + (size_t)Nh * 128;
  unsigned short* WsT = WmT + 256 * 256;
  float* c1 = (float*)(WsT + 256 * 128);
  float* c2 = c1 + Mp;
  int*   ro1 = (int*)(c2 + Mp);
  int*   ro2 = ro1 + (M + 1);

  const int nX4 = M * 256 / 4, nH4 = Nh * 128 / 4;
  const int bX  = (nX4 + 255) / 256;
  const int bH  = (nH4 + 255) / 256;
  const int bE1 = (E + 255) / 256;
  const int bE2 = (E2 + 255) / 256;
  const int prep_blocks = bX + bH + bE1 + bE2 + 64 + 32;

  prep_all<<<prep_blocks, 256, 0, stream>>>(
      node_features, hedge_features,
      node_receivers, E, h2n_receivers, E2, M,
      Wm, Ws, Xb, Hb, ro1, ro2, WmT, WsT, nX4, nH4);

  // One wave per node: 4 waves per block.
  scatter_node_seg<<<(M + 3) / 4, 256, 0, stream>>>(
      Xb, node_senders, node_conv, ro1, Ab, c1, M);
  scatter_hedge_seg<<<(M + 3) / 4, 256, 0, stream>>>(
      Hb, h2n_senders, h2n_conv, ro2, Bb, c2, M);

  gemm_combine_mfma<<<Mp / 256, 512, 0, stream>>>(
      Ab, Bb, c1, c2, WmT, bm, WsT, bs, out, M);
}

// Round 11
// 122.311 us; speedup vs baseline: 1.8327x; 1.0124x over previous
//
#include <hip/hip_runtime.h>

// ---------------------------------------------------------------------------
// Pipeline (algebraically restructured from the reference):
//   Xb = bf16(node_features), Hb = bf16(hedge_features)     (prep_all)
//   A[n,:]  = sum_{e: rcv=n} conv_e * Xb[snd_e,:]           (f32 acc -> bf16)
//   c1[n]   = sum_{e: rcv=n} conv_e
//   B[n,:]  = sum_{e2} conv2_e * Hb[snd_e,:]                (f32 acc -> bf16)
//   c2[n]   = sum conv2_e
//   out     = (A@Wm + c1*bm) .* (B@Ws + c2*bs)   -- bf16 MFMA, f32 accum
//
// R11: R9 scatter loop structure (16/4/1 unmasked batches — fastest measured)
// + nontemporal stores for A/B/c (stop the 25.6 MB output stream from
// write-allocate-evicting the L2-resident gather table) + nontemporal loads
// for the read-once idx streams + R10's A/B-VGPR-resident GEMM with nt out.
// ---------------------------------------------------------------------------

typedef __attribute__((ext_vector_type(8))) short bf16x8;
typedef __attribute__((ext_vector_type(4))) float f32x4;
typedef __attribute__((ext_vector_type(4))) unsigned short u16x4;
typedef __attribute__((ext_vector_type(2))) unsigned short u16x2;

static __device__ __forceinline__ unsigned short f2bf(float f) {
  unsigned u = __float_as_uint(f);
  u += 0x7fff + ((u >> 16) & 1);          // round-to-nearest-even
  return (unsigned short)(u >> 16);
}
static __device__ __forceinline__ float bf2f(unsigned short h) {
  return __uint_as_float((unsigned)h << 16);
}

// ---------------------------------------------------------------------------
// prep_all: blockIdx ranges ->
//   [0,bX)     : cvt X f32 -> Xb bf16
//   [bX,+bH)   : cvt H f32 -> Hb bf16
//   [..,+bE1)  : row offsets for node_receivers
//   [..,+bE2)  : row offsets for h2n_receivers
//   [..,+64)   : transpose Wm (256x256) -> WmT bf16
//   [..,+32)   : transpose Ws (128x256) -> WsT bf16
// ---------------------------------------------------------------------------
__global__ __launch_bounds__(256) void prep_all(
    const float* __restrict__ X, const float* __restrict__ H,
    const int* __restrict__ rcv1, int E1,
    const int* __restrict__ rcv2, int E2, int N,
    const float* __restrict__ Wm, const float* __restrict__ Ws,
    unsigned short* __restrict__ Xb, unsigned short* __restrict__ Hb,
    int* __restrict__ ro1, int* __restrict__ ro2,
    unsigned short* __restrict__ WmT, unsigned short* __restrict__ WsT,
    int nX4, int nH4)
{
  __shared__ float t[32][33];
  const int tid = (int)threadIdx.x;
  int b = (int)blockIdx.x;

  const int bX  = (nX4 + 255) / 256;
  const int bH  = (nH4 + 255) / 256;
  const int bE1 = (E1 + 255) / 256;
  const int bE2 = (E2 + 255) / 256;

  if (b < bX) {                       // ---- cvt X ----
    const int i = b * 256 + tid;
    if (i < nX4) {
      const float4 v = reinterpret_cast<const float4*>(X)[i];
      reinterpret_cast<ushort4*>(Xb)[i] =
          make_ushort4(f2bf(v.x), f2bf(v.y), f2bf(v.z), f2bf(v.w));
    }
    return;
  }
  b -= bX;
  if (b < bH) {                       // ---- cvt H ----
    const int i = b * 256 + tid;
    if (i < nH4) {
      const float4 v = reinterpret_cast<const float4*>(H)[i];
      reinterpret_cast<ushort4*>(Hb)[i] =
          make_ushort4(f2bf(v.x), f2bf(v.y), f2bf(v.z), f2bf(v.w));
    }
    return;
  }
  b -= bH;
  if (b < bE1) {                      // ---- row offsets 1 ----
    const int e = b * 256 + tid;
    if (e < E1) {
      const int c = rcv1[e];
      const int p = (e == 0) ? -1 : rcv1[e - 1];
      for (int n = p + 1; n <= c; ++n) ro1[n] = e;
      if (e == E1 - 1)
        for (int n = c + 1; n <= N; ++n) ro1[n] = E1;
    }
    return;
  }
  b -= bE1;
  if (b < bE2) {                      // ---- row offsets 2 ----
    const int e = b * 256 + tid;
    if (e < E2) {
      const int c = rcv2[e];
      const int p = (e == 0) ? -1 : rcv2[e - 1];
      for (int n = p + 1; n <= c; ++n) ro2[n] = e;
      if (e == E2 - 1)
        for (int n = c + 1; n <= N; ++n) ro2[n] = E2;
    }
    return;
  }
  b -= bE2;
  {
    // ---- weight transposes: Wm tiles [0,64), Ws tiles [64,96) ----
    const float* W; unsigned short* WT; int K, Nn, tile;
    if (b < 64) { W = Wm; WT = WmT; K = 256; Nn = 256; tile = b; }
    else        { W = Ws; WT = WsT; K = 128; Nn = 256; tile = b - 64; }
    const int ntiles_n = Nn / 32;
    const int n0 = (tile % ntiles_n) * 32;
    const int k0 = (tile / ntiles_n) * 32;
    const int tx = tid & 31, ty = tid >> 5;   // 32 x 8
#pragma unroll
    for (int i = 0; i < 32; i += 8)
      t[ty + i][tx] = W[(size_t)(k0 + ty + i) * Nn + n0 + tx];
    __syncthreads();
#pragma unroll
    for (int i = 0; i < 32; i += 8)
      WT[(size_t)(n0 + ty + i) * K + k0 + tx] = f2bf(t[tx][ty + i]);
  }
}

// One wave per node, C=256 bf16 channels (ushort4 per lane). No atomics.
// R9 loop structure (16/4/1 unmasked); nt loads for idx streams, nt store
// for A so the output stream doesn't evict the L2-resident gather table.
__global__ __launch_bounds__(256) void scatter_node_seg(
    const unsigned short* __restrict__ X,   // [Nsrc,256] bf16
    const int* __restrict__ snd,
    const float* __restrict__ conv,
    const int* __restrict__ row_start,      // [N+1]
    unsigned short* __restrict__ A,         // [Mp,256] bf16
    float* __restrict__ csum,               // [Mp]
    int N)
{
  const int lane = threadIdx.x & 63;
  const int node = __builtin_amdgcn_readfirstlane(
      (int)blockIdx.x * 4 + ((int)threadIdx.x >> 6));
  if (node >= N) return;
  const int lo = row_start[node];
  const int hi = row_start[node + 1];

  const unsigned short* Xl = X + lane * 4;
  float4 acc = make_float4(0.f, 0.f, 0.f, 0.f);
  float cacc = 0.f;

  int e = lo;
  for (; e + 16 <= hi; e += 16) {
    int s[16]; float cv[16]; ushort4 x[16];
#pragma unroll
    for (int j = 0; j < 16; ++j) s[j] = __builtin_nontemporal_load(snd + e + j);
#pragma unroll
    for (int j = 0; j < 16; ++j) cv[j] = __builtin_nontemporal_load(conv + e + j);
#pragma unroll
    for (int j = 0; j < 16; ++j)
      x[j] = *reinterpret_cast<const ushort4*>(Xl + (size_t)s[j] * 256);
#pragma unroll
    for (int j = 0; j < 16; ++j) {
      acc.x = fmaf(cv[j], bf2f(x[j].x), acc.x);
      acc.y = fmaf(cv[j], bf2f(x[j].y), acc.y);
      acc.z = fmaf(cv[j], bf2f(x[j].z), acc.z);
      acc.w = fmaf(cv[j], bf2f(x[j].w), acc.w);
      cacc += cv[j];
    }
  }
  for (; e + 4 <= hi; e += 4) {
    int s[4]; float cv[4]; ushort4 x[4];
#pragma unroll
    for (int j = 0; j < 4; ++j) s[j] = __builtin_nontemporal_load(snd + e + j);
#pragma unroll
    for (int j = 0; j < 4; ++j) cv[j] = __builtin_nontemporal_load(conv + e + j);
#pragma unroll
    for (int j = 0; j < 4; ++j)
      x[j] = *reinterpret_cast<const ushort4*>(Xl + (size_t)s[j] * 256);
#pragma unroll
    for (int j = 0; j < 4; ++j) {
      acc.x = fmaf(cv[j], bf2f(x[j].x), acc.x);
      acc.y = fmaf(cv[j], bf2f(x[j].y), acc.y);
      acc.z = fmaf(cv[j], bf2f(x[j].z), acc.z);
      acc.w = fmaf(cv[j], bf2f(x[j].w), acc.w);
      cacc += cv[j];
    }
  }
  for (; e < hi; ++e) {
    const int s = snd[e];
    const float cv = conv[e];
    const ushort4 x = *reinterpret_cast<const ushort4*>(Xl + (size_t)s * 256);
    acc.x = fmaf(cv, bf2f(x.x), acc.x);
    acc.y = fmaf(cv, bf2f(x.y), acc.y);
    acc.z = fmaf(cv, bf2f(x.z), acc.z);
    acc.w = fmaf(cv, bf2f(x.w), acc.w);
    cacc += cv;
  }

  u16x4 r;
  r[0] = f2bf(acc.x); r[1] = f2bf(acc.y);
  r[2] = f2bf(acc.z); r[3] = f2bf(acc.w);
  __builtin_nontemporal_store(
      r, reinterpret_cast<u16x4*>(A + (size_t)node * 256 + lane * 4));
  if (lane == 0) __builtin_nontemporal_store(cacc, csum + node);
}

// One wave per node, C=128 bf16 channels (ushort2 per lane). No atomics.
// R9 loop structure (8/1); nt idx loads, nt B store.
__global__ __launch_bounds__(256) void scatter_hedge_seg(
    const unsigned short* __restrict__ X,   // [Nsrc,128] bf16
    const int* __restrict__ snd,
    const float* __restrict__ conv,
    const int* __restrict__ row_start,      // [N+1]
    unsigned short* __restrict__ B,         // [Mp,128] bf16
    float* __restrict__ csum,               // [Mp]
    int N)
{
  const int lane = threadIdx.x & 63;
  const int node = __builtin_amdgcn_readfirstlane(
      (int)blockIdx.x * 4 + ((int)threadIdx.x >> 6));
  if (node >= N) return;
  const int lo = row_start[node];
  const int hi = row_start[node + 1];

  const unsigned short* Xl = X + lane * 2;
  float2 acc = make_float2(0.f, 0.f);
  float cacc = 0.f;

  int e = lo;
  for (; e + 8 <= hi; e += 8) {
    int s[8]; float cv[8]; ushort2 x[8];
#pragma unroll
    for (int j = 0; j < 8; ++j) s[j] = __builtin_nontemporal_load(snd + e + j);
#pragma unroll
    for (int j = 0; j < 8; ++j) cv[j] = __builtin_nontemporal_load(conv + e + j);
#pragma unroll
    for (int j = 0; j < 8; ++j)
      x[j] = *reinterpret_cast<const ushort2*>(Xl + (size_t)s[j] * 128);
#pragma unroll
    for (int j = 0; j < 8; ++j) {
      acc.x = fmaf(cv[j], bf2f(x[j].x), acc.x);
      acc.y = fmaf(cv[j], bf2f(x[j].y), acc.y);
      cacc += cv[j];
    }
  }
  for (; e < hi; ++e) {
    const int s = snd[e];
    const float cv = conv[e];
    const ushort2 x = *reinterpret_cast<const ushort2*>(Xl + (size_t)s * 128);
    acc.x = fmaf(cv, bf2f(x.x), acc.x);
    acc.y = fmaf(cv, bf2f(x.y), acc.y);
    cacc += cv;
  }

  u16x2 r;
  r[0] = f2bf(acc.x); r[1] = f2bf(acc.y);
  __builtin_nontemporal_store(
      r, reinterpret_cast<u16x2*>(B + (size_t)node * 128 + lane * 2));
  if (lane == 0) __builtin_nontemporal_store(cacc, csum + node);
}

// ---------------------------------------------------------------------------
// MFMA dual-GEMM + bias + Hadamard, A/B-resident version (R10).
// Grid: Mp/256 blocks of 512 threads (8 waves). Each block owns a 256-row
// tile; A/B fragments for the whole K are loaded ONCE into VGPRs, then the
// block loops over 4 col-blocks of 64, staging that W slice in LDS.
// nt stores for the 51 MB out stream (write-once, never re-read).
// mfma_f32_16x16x32_bf16 fragments:
//   A-frag: row = lane&15, k = 8*(lane>>4) + j
//   B-frag: col = lane&15, k = 8*(lane>>4) + j
//   C/D   : col = lane&15, row = 4*(lane>>4) + reg   [m89-verified]
// ---------------------------------------------------------------------------
__global__ __launch_bounds__(512) void gemm_combine_mfma(
    const unsigned short* __restrict__ A,    // [Mp,256] bf16
    const unsigned short* __restrict__ B,    // [Mp,128] bf16
    const float* __restrict__ c1,            // [Mp]
    const float* __restrict__ c2,            // [Mp]
    const unsigned short* __restrict__ WmT,  // [256,256] bf16 (N-major)
    const float* __restrict__ bm,            // [256]
    const unsigned short* __restrict__ WsT,  // [256,128] bf16 (N-major)
    const float* __restrict__ bs,            // [256]
    float* __restrict__ out,                 // [M,256]
    int M)
{
  __shared__ unsigned short lWm[64][264];    // 64 cols x 256 K, +8 pad
  __shared__ unsigned short lWs[64][136];    // 64 cols x 128 K, +8 pad

  const int tid  = (int)threadIdx.x;
  const int lane = tid & 63;
  const int wv   = tid >> 6;          // 0..7
  const int l15  = lane & 15;
  const int lg   = lane >> 4;         // 0..3
  const int m0   = blockIdx.x * 256;

  const int rowA = m0 + wv * 32 + l15;

  // ---- load A/B fragments for the whole K once (held in VGPRs) ----
  bf16x8 afrag[2][8];
  bf16x8 bfrag[2][4];
#pragma unroll
  for (int k8 = 0; k8 < 8; ++k8) {
    const int ko = k8 * 32 + lg * 8;
    afrag[0][k8] = *reinterpret_cast<const bf16x8*>(A + (size_t)rowA * 256 + ko);
    afrag[1][k8] = *reinterpret_cast<const bf16x8*>(A + (size_t)(rowA + 16) * 256 + ko);
  }
#pragma unroll
  for (int k8 = 0; k8 < 4; ++k8) {
    const int ko = k8 * 32 + lg * 8;
    bfrag[0][k8] = *reinterpret_cast<const bf16x8*>(B + (size_t)rowA * 128 + ko);
    bfrag[1][k8] = *reinterpret_cast<const bf16x8*>(B + (size_t)(rowA + 16) * 128 + ko);
  }

  // ---- per-row conv sums for the bias terms (rows this lane stores) ----
  float k1v[2][4], k2v[2][4];
#pragma unroll
  for (int ms = 0; ms < 2; ++ms)
#pragma unroll
    for (int r = 0; r < 4; ++r) {
      const int row = m0 + wv * 32 + ms * 16 + lg * 4 + r;
      const bool v = row < M;
      k1v[ms][r] = v ? c1[row] : 0.f;
      k2v[ms][r] = v ? c2[row] : 0.f;
    }

  // ---- loop over 4 col-blocks of 64 ----
  for (int cb = 0; cb < 4; ++cb) {
    const int colBlk = cb * 64;
    __syncthreads();                         // LDS safe to overwrite
#pragma unroll
    for (int i = 0; i < 4; ++i) {            // lWm: 2048 x 16B
      const int idx = tid + i * 512;
      const int c = idx >> 5, k8b = (idx & 31) << 3;
      *reinterpret_cast<bf16x8*>(&lWm[c][k8b]) =
          *reinterpret_cast<const bf16x8*>(WmT + (size_t)(colBlk + c) * 256 + k8b);
    }
#pragma unroll
    for (int i = 0; i < 2; ++i) {            // lWs: 1024 x 16B
      const int idx = tid + i * 512;
      const int c = idx >> 4, k8b = (idx & 15) << 3;
      *reinterpret_cast<bf16x8*>(&lWs[c][k8b]) =
          *reinterpret_cast<const bf16x8*>(WsT + (size_t)(colBlk + c) * 128 + k8b);
    }
    __syncthreads();

    f32x4 accM[2][4];
    f32x4 accS[2][4];
#pragma unroll
    for (int ms = 0; ms < 2; ++ms)
#pragma unroll
      for (int n = 0; n < 4; ++n) {
        accM[ms][n] = (f32x4)0.f;
        accS[ms][n] = (f32x4)0.f;
      }

#pragma unroll
    for (int k8 = 0; k8 < 8; ++k8) {
      const int ko = k8 * 32 + lg * 8;
#pragma unroll
      for (int n = 0; n < 4; ++n) {
        const bf16x8 w = *reinterpret_cast<const bf16x8*>(&lWm[l15 + n * 16][ko]);
        accM[0][n] = __builtin_amdgcn_mfma_f32_16x16x32_bf16(afrag[0][k8], w, accM[0][n], 0, 0, 0);
        accM[1][n] = __builtin_amdgcn_mfma_f32_16x16x32_bf16(afrag[1][k8], w, accM[1][n], 0, 0, 0);
      }
    }
#pragma unroll
    for (int k8 = 0; k8 < 4; ++k8) {
      const int ko = k8 * 32 + lg * 8;
#pragma unroll
      for (int n = 0; n < 4; ++n) {
        const bf16x8 w = *reinterpret_cast<const bf16x8*>(&lWs[l15 + n * 16][ko]);
        accS[0][n] = __builtin_amdgcn_mfma_f32_16x16x32_bf16(bfrag[0][k8], w, accS[0][n], 0, 0, 0);
        accS[1][n] = __builtin_amdgcn_mfma_f32_16x16x32_bf16(bfrag[1][k8], w, accS[1][n], 0, 0, 0);
      }
    }

    // ---- epilogue for this col-block ----
    float bmv[4], bsv[4];
#pragma unroll
    for (int n = 0; n < 4; ++n) {
      bmv[n] = bm[colBlk + n * 16 + l15];
      bsv[n] = bs[colBlk + n * 16 + l15];
    }
#pragma unroll
    for (int ms = 0; ms < 2; ++ms) {
      const int rbase = m0 + wv * 32 + ms * 16 + lg * 4;
#pragma unroll
      for (int r = 0; r < 4; ++r) {
        const int row = rbase + r;
        if (row < M) {
#pragma unroll
          for (int n = 0; n < 4; ++n) {
            const int col = colBlk + n * 16 + l15;
            const float mv = accM[ms][n][r] + k1v[ms][r] * bmv[n];
            const float sv = accS[ms][n][r] + k2v[ms][r] * bsv[n];
            __builtin_nontemporal_store(mv * sv, out + (size_t)row * 256 + col);
          }
        }
      }
    }
  }
}

extern "C" void kernel_launch(void* const* d_in, const int* in_sizes, int n_in,
                              void* d_out, int out_size, void* d_ws, size_t ws_size,
                              hipStream_t stream) {
  const float* node_features  = (const float*)d_in[0];   // [50000,256]
  const float* hedge_features = (const float*)d_in[1];   // [25000,128]
  const int*   node_senders   = (const int*)d_in[2];     // [E]
  const int*   node_receivers = (const int*)d_in[3];     // [E] sorted
  const float* node_conv      = (const float*)d_in[4];   // [E]
  const int*   h2n_senders    = (const int*)d_in[5];     // [E2]
  const int*   h2n_receivers  = (const int*)d_in[6];     // [E2] sorted
  const float* h2n_conv       = (const float*)d_in[7];   // [E2]
  const float* Wm             = (const float*)d_in[8];   // [256,256]
  const float* bm             = (const float*)d_in[9];   // [256]
  const float* Ws             = (const float*)d_in[10];  // [128,256]
  const float* bs             = (const float*)d_in[11];  // [256]
  float* out = (float*)d_out;

  const int M   = in_sizes[0] / 256;       // 50000 nodes
  const int Nh  = in_sizes[1] / 128;       // 25000 hedges
  const int E   = in_sizes[2];             // 800000
  const int E2  = in_sizes[5];             // 400000
  const int Mp  = ((M + 255) / 256) * 256; // padded rows for 256-row GEMM tiles

  // Workspace layout (bf16 = unsigned short):
  //   A[Mp,256] | B[Mp,128] | Xb[M,256] | Hb[Nh,128] | WmT[256,256]
  //   | WsT[256,128] | c1 f32[Mp] | c2 f32[Mp] | ro1 [M+1] | ro2 [M+1]
  unsigned short* Ab  = (unsigned short*)d_ws;
  unsigned short* Bb  = Ab + (size_t)Mp * 256;
  unsigned short* Xb  = Bb + (size_t)Mp * 128;
  unsigned short* Hb  = Xb + (size_t)M * 256;
  unsigned short* WmT = Hb + (size_t)Nh * 128;
  unsigned short* WsT = WmT + 256 * 256;
  float* c1 = (float*)(WsT + 256 * 128);
  float* c2 = c1 + Mp;
  int*   ro1 = (int*)(c2 + Mp);
  int*   ro2 = ro1 + (M + 1);

  const int nX4 = M * 256 / 4, nH4 = Nh * 128 / 4;
  const int bX  = (nX4 + 255) / 256;
  const int bH  = (nH4 + 255) / 256;
  const int bE1 = (E + 255) / 256;
  const int bE2 = (E2 + 255) / 256;
  const int prep_blocks = bX + bH + bE1 + bE2 + 64 + 32;

  prep_all<<<prep_blocks, 256, 0, stream>>>(
      node_features, hedge_features,
      node_receivers, E, h2n_receivers, E2, M,
      Wm, Ws, Xb, Hb, ro1, ro2, WmT, WsT, nX4, nH4);

  // One wave per node: 4 waves per block.
  scatter_node_seg<<<(M + 3) / 4, 256, 0, stream>>>(
      Xb, node_senders, node_conv, ro1, Ab, c1, M);
  scatter_hedge_seg<<<(M + 3) / 4, 256, 0, stream>>>(
      Hb, h2n_senders, h2n_conv, ro2, Bb, c2, M);

  gemm_combine_mfma<<<Mp / 256, 512, 0, stream>>>(
      Ab, Bb, c1, c2, WmT, bm, WsT, bs, out, M);
}